// Round 8
// baseline (228.323 us; speedup 1.0000x reference)
//
#include <hip/hip_runtime.h>
#include <math.h>

// (B,L,H,P) = (4,4096,512,512)
#define Bz 4
#define Lz 4096
#define Hz 512
#define Pz 512
#define Nz (Bz*Lz)          // 16384 rows
#define CL 64               // scan chunk length
#define NC (Lz/CL)          // 64 chunks
#define CS (Bz*NC*Pz)       // 131072 carry slots
#define EPSf 1e-5f

typedef unsigned short u16;
typedef unsigned int   u32;
typedef __attribute__((ext_vector_type(8))) short bf16x8;
typedef __attribute__((ext_vector_type(4))) float f32x4;

__device__ __forceinline__ float gelu_exact(float x){
    return 0.5f * x * (1.0f + erff(x * 0.70710678118654752f));
}
__device__ __forceinline__ u16 f2b(float f){
    union { float f; u32 u; } v; v.f = f;
    u32 u = v.u;
    u32 r = (u + 0x7FFFu + ((u >> 16) & 1u)) >> 16;   // RTNE
    return (u16)r;
}
__device__ __forceinline__ float b2f(u16 h){
    union { u32 u; float f; } v; v.u = ((u32)h) << 16; return v.f;
}
__device__ __forceinline__ float cvt_in(float x){ return x; }
__device__ __forceinline__ float cvt_in(u16 x){ return b2f(x); }

__device__ __forceinline__ void gload_lds16(const u16* g, u16* l){
    __builtin_amdgcn_global_load_lds(
        (const __attribute__((address_space(1))) void*)g,
        (__attribute__((address_space(3))) void*)l, 16, 0, 0);
}

// ---------------- setup: per-state SSM params ----------------
__global__ void setup_kernel(const float* __restrict__ Lre, const float* __restrict__ Lim,
                             const float* __restrict__ log_step,
                             float* __restrict__ prm){
    int p = blockIdx.x*blockDim.x + threadIdx.x;
    if (p >= Pz) return;
    float lr = Lre[p], li = Lim[p];
    float dt = expf(log_step[p]);
    float ar = lr*dt, ai = li*dt;
    float e = expf(ar);
    float Abr = e*cosf(ai), Abi = e*sinf(ai);   // Lambda_bar
    prm[p]        = Abr;
    prm[Pz + p]   = Abi;
    float nr = Abr - 1.0f, ni = Abi;
    float d2 = lr*lr + li*li;
    prm[2*Pz + p] = (nr*lr + ni*li)/d2;   // fRe
    prm[3*Pz + p] = (ni*lr - nr*li)/d2;   // fIm
    float arC = ar*(float)CL, aiC = ai*(float)CL;
    float eC = expf(arC);
    prm[4*Pz + p] = eC*cosf(aiC);         // ApowRe
    prm[5*Pz + p] = eC*sinf(aiC);         // ApowIm
}

// ---------------- merged weight converts ----------------
__global__ __launch_bounds__(256) void cvt_all(const float* __restrict__ B_re,
                                               const float* __restrict__ B_im,
                                               const float* __restrict__ C_re,
                                               const float* __restrict__ C_im,
                                               const float* __restrict__ W_enc,
                                               const float* __restrict__ W_dec,
                                               u16* __restrict__ Bcat,
                                               u16* __restrict__ Ccat,
                                               u16* __restrict__ Wenc,
                                               u16* __restrict__ Wdec){
    const int Q = 512*512;
    int i = blockIdx.x*256 + threadIdx.x;
    if (i < Q){ Bcat[i] = f2b(B_re[i]); return; }
    i -= Q;
    if (i < Q){ Bcat[Q + i] = f2b(B_im[i]); return; }
    i -= Q;
    if (i < Q){
        int h = i >> 9, p = i & 511;
        Ccat[(size_t)h*1024 + p]       = f2b(C_re[i]);
        Ccat[(size_t)h*1024 + 512 + p] = f2b(-C_im[i]);
        return;
    }
    i -= Q;
    if (i < 2*Q){ Wenc[i] = f2b(W_enc[i]); return; }
    i -= 2*Q;
    Wdec[i] = f2b(W_dec[i]);
}

// ---------------- LayerNorm: f32 in -> bf16 out (LN1 only) ----------------
__global__ __launch_bounds__(256) void ln_kernel(const float* __restrict__ in,
                                                 const float* __restrict__ w,
                                                 const float* __restrict__ b,
                                                 u16* __restrict__ ob){
    int row = blockIdx.x;
    int tid = threadIdx.x;
    const float* r = in + (size_t)row*Hz;
    float v0 = r[tid], v1 = r[tid+256];
    float s = v0+v1, q = v0*v0+v1*v1;
    #pragma unroll
    for (int o=32;o;o>>=1){ s += __shfl_down(s,o); q += __shfl_down(q,o); }
    __shared__ float ss[4], sq[4];
    __shared__ float mu_s, rs_s;
    int wid = tid>>6, lane = tid&63;
    if (lane==0){ ss[wid]=s; sq[wid]=q; }
    __syncthreads();
    if (tid==0){
        float S=ss[0]+ss[1]+ss[2]+ss[3];
        float Q=sq[0]+sq[1]+sq[2]+sq[3];
        float mu = S/(float)Hz;
        float var = Q/(float)Hz - mu*mu;
        mu_s = mu; rs_s = rsqrtf(var + EPSf);
    }
    __syncthreads();
    float mu = mu_s, rs = rs_s;
    u16* o = ob + (size_t)row*Hz;
    o[tid]     = f2b((v0-mu)*rs*w[tid]    +b[tid]);
    o[tid+256] = f2b((v1-mu)*rs*w[tid+256]+b[tid+256]);
}

// ============ 64-row full-width MFMA kernels ============
// All: 512 threads (8 waves), block owns 64 consecutive rows, grid 256 (1/CU).
// LDS tiles [rows][32] bf16 with the R7-HW-verified 0-conflict swizzle:
// stage colE = 8*((lane&3)^((lane>>3)&3)); read lcol = 8*((l>>4)^((l>>1)&3)).

// stage [64][32] A-tile (4KB), threads 0..255 only
__device__ __forceinline__ void stageA64(const u16* __restrict__ src, int ld,
                                         int row0, int kt, u16* lds){
    int tid = threadIdx.x;
    if (tid < 256){
        int lane = tid & 63, c = tid >> 6;              // c 0..3, 16 rows each
        int r = c*16 + (lane >> 2);
        int colE = 8*((lane & 3) ^ ((lane >> 3) & 3));
        gload_lds16(src + (size_t)(row0 + r)*ld + kt + colE, lds + c*512);
    }
}
// stage [512][32] B-tile (32KB), all 512 threads, 4 chunks each
__device__ __forceinline__ void stageB512(const u16* __restrict__ src, int ld,
                                          int row0, int kt, u16* lds){
    int lane = threadIdx.x & 63, w = threadIdx.x >> 6;
    #pragma unroll
    for (int q = 0; q < 4; ++q){
        int c = w + q*8;                                // 0..31, 16 rows each
        int r = c*16 + (lane >> 2);
        int colE = 8*((lane & 3) ^ ((lane >> 3) & 3));
        gload_lds16(src + (size_t)(row0 + r)*ld + kt + colE, lds + c*512);
    }
}

// ---- GEMM1: g[n][ms*512 + m] = fxb @ Bcat^T, 64 rows/block ----
__global__ __launch_bounds__(512, 2)
void gemm1_row(const u16* __restrict__ A, const u16* __restrict__ Bw,
               u16* __restrict__ outB){
    __shared__ u16 AL[2][64*32];
    __shared__ u16 BL[2][512*32];
    int lid = blockIdx.x;
    int gdx = (lid & 7)*32 + (lid >> 3);     // XCD swizzle, grid 256
    int n0 = gdx * 64;
    int l = threadIdx.x & 63, w = threadIdx.x >> 6;
    int lrow = l & 15;
    int lcol = 8*((l >> 4) ^ ((l >> 1) & 3));
    int er = (l >> 4)*4, ec = l & 15;

    for (int ms = 0; ms < 2; ++ms){
        f32x4 acc[4][4];
        #pragma unroll
        for (int i=0;i<4;++i)
            #pragma unroll
            for (int j=0;j<4;++j) acc[i][j] = (f32x4)(0.f);
        stageA64(A, 512, n0, 0, &AL[0][0]);
        stageB512(Bw, 512, ms*512, 0, &BL[0][0]);
        __syncthreads();
        for (int T=0; T<16; ++T){
            int buf = T & 1, nb = buf ^ 1;
            if (T+1 < 16){
                stageA64(A, 512, n0, (T+1)*32, &AL[nb][0]);
                stageB512(Bw, 512, ms*512, (T+1)*32, &BL[nb][0]);
            }
            bf16x8 bf4[4];
            #pragma unroll
            for (int fn=0; fn<4; ++fn)
                bf4[fn] = *(const bf16x8*)&BL[buf][(w*64 + fn*16 + lrow)*32 + lcol];
            #pragma unroll
            for (int fm=0; fm<4; ++fm){
                bf16x8 af = *(const bf16x8*)&AL[buf][(fm*16 + lrow)*32 + lcol];
                #pragma unroll
                for (int fn=0; fn<4; ++fn)
                    acc[fm][fn] = __builtin_amdgcn_mfma_f32_16x16x32_bf16(af, bf4[fn], acc[fm][fn], 0,0,0);
            }
            __syncthreads();
        }
        #pragma unroll
        for (int fm=0; fm<4; ++fm)
            #pragma unroll
            for (int fn=0; fn<4; ++fn)
                #pragma unroll
                for (int q=0; q<4; ++q){
                    int n = n0 + fm*16 + er + q;
                    int m = ms*512 + w*64 + fn*16 + ec;
                    outB[(size_t)n*1024 + m] = f2b(acc[fm][fn][q]);
                }
    }
}

// ---- GEMM2 + EY + LN2: fx2b = LN2(gelu(2*(xs@Ccat^T)+D*fx)+fx) ----
__global__ __launch_bounds__(512, 2)
void gemm2_ln(const u16* __restrict__ A, const u16* __restrict__ Bw,
              const u16* __restrict__ fxB, const float* __restrict__ Dv,
              const float* __restrict__ w2, const float* __restrict__ b2,
              u16* __restrict__ outB){
    __shared__ u16 AL[2][64*32];
    __shared__ u16 BL[2][512*32];
    int lid = blockIdx.x;
    int gdx = (lid & 7)*32 + (lid >> 3);
    int n0 = gdx * 64;
    int l = threadIdx.x & 63, w = threadIdx.x >> 6;
    int lrow = l & 15;
    int lcol = 8*((l >> 4) ^ ((l >> 1) & 3));
    int er = (l >> 4)*4, ec = l & 15;

    f32x4 acc[4][4];
    #pragma unroll
    for (int i=0;i<4;++i)
        #pragma unroll
        for (int j=0;j<4;++j) acc[i][j] = (f32x4)(0.f);
    stageA64(A, 1024, n0, 0, &AL[0][0]);
    stageB512(Bw, 1024, 0, 0, &BL[0][0]);
    __syncthreads();
    for (int T=0; T<32; ++T){
        int buf = T & 1, nb = buf ^ 1;
        if (T+1 < 32){
            stageA64(A, 1024, n0, (T+1)*32, &AL[nb][0]);
            stageB512(Bw, 1024, 0, (T+1)*32, &BL[nb][0]);
        }
        bf16x8 bf4[4];
        #pragma unroll
        for (int fn=0; fn<4; ++fn)
            bf4[fn] = *(const bf16x8*)&BL[buf][(w*64 + fn*16 + lrow)*32 + lcol];
        #pragma unroll
        for (int fm=0; fm<4; ++fm){
            bf16x8 af = *(const bf16x8*)&AL[buf][(fm*16 + lrow)*32 + lcol];
            #pragma unroll
            for (int fn=0; fn<4; ++fn)
                acc[fm][fn] = __builtin_amdgcn_mfma_f32_16x16x32_bf16(af, bf4[fn], acc[fm][fn], 0,0,0);
        }
        __syncthreads();
    }

    // EY epilogue in-register: acc <- h = gelu(2*acc + D*fx) + fx
    float dvc[4], fxv;
    #pragma unroll
    for (int fn=0; fn<4; ++fn) dvc[fn] = Dv[w*64 + fn*16 + ec];
    #pragma unroll
    for (int fm=0; fm<4; ++fm)
        #pragma unroll
        for (int fn=0; fn<4; ++fn)
            #pragma unroll
            for (int q=0; q<4; ++q){
                int n = n0 + fm*16 + er + q;
                int m = w*64 + fn*16 + ec;
                fxv = b2f(fxB[(size_t)n*Hz + m]);
                float y = 2.0f*acc[fm][fn][q] + dvc[fn]*fxv;
                acc[fm][fn][q] = gelu_exact(y) + fxv;
            }

    // LN2 over the block's 64 complete rows
    float* S = (float*)&BL[0][0];    // [0..63]=sum, [64..127]=sumsq, [128..191]=mu, [192..255]=rs
    int tid = threadIdx.x;
    if (tid < 128) S[tid] = 0.f;
    __syncthreads();
    #pragma unroll
    for (int fm=0; fm<4; ++fm)
        #pragma unroll
        for (int q=0; q<4; ++q){
            float sv = 0.f, qv = 0.f;
            #pragma unroll
            for (int fn=0; fn<4; ++fn){ float h = acc[fm][fn][q]; sv += h; qv += h*h; }
            #pragma unroll
            for (int o=1; o<16; o<<=1){ sv += __shfl_xor(sv, o); qv += __shfl_xor(qv, o); }
            if (ec == 0){
                int row = fm*16 + er + q;
                atomicAdd(&S[row], sv);
                atomicAdd(&S[64 + row], qv);
            }
        }
    __syncthreads();
    if (tid < 64){
        float mu = S[tid] * (1.0f/512.0f);
        float var = S[64 + tid] * (1.0f/512.0f) - mu*mu;
        S[128 + tid] = mu;
        S[192 + tid] = rsqrtf(var + EPSf);
    }
    __syncthreads();
    float lw[4], lb[4];
    #pragma unroll
    for (int fn=0; fn<4; ++fn){ int m = w*64 + fn*16 + ec; lw[fn] = w2[m]; lb[fn] = b2[m]; }
    #pragma unroll
    for (int fm=0; fm<4; ++fm)
        #pragma unroll
        for (int q=0; q<4; ++q){
            int row = fm*16 + er + q;
            float mu = S[128 + row], rs = S[192 + row];
            #pragma unroll
            for (int fn=0; fn<4; ++fn){
                int m = w*64 + fn*16 + ec;
                float v = (acc[fm][fn][q] - mu)*rs*lw[fn] + lb[fn];
                outB[(size_t)(n0 + row)*Hz + m] = f2b(v);
            }
        }
}

// ---- MLP megakernel: out = (a*gelu(g)) @ Wdec^T + fx2, e=[a|g]=fx2@Wenc^T ----
__global__ __launch_bounds__(512, 2)
void mlp_fused(const u16* __restrict__ A /*fx2b*/, const u16* __restrict__ W1,
               const u16* __restrict__ W2, float* __restrict__ outF){
    __shared__ u16 AL[2][64*32];     // 8KB
    __shared__ u16 BL[2][512*32];    // 64KB
    __shared__ u16 FF[64*512];       // 64KB
    int lid = blockIdx.x;
    int gdx = (lid & 7)*32 + (lid >> 3);
    int n0 = gdx * 64;
    int l = threadIdx.x & 63, w = threadIdx.x >> 6;
    int lrow = l & 15;
    int lcol = 8*((l >> 4) ^ ((l >> 1) & 3));
    int er = (l >> 4)*4, ec = l & 15;

    f32x4 accA[4][4], accG[4][4];
    #pragma unroll
    for (int i=0;i<4;++i)
        #pragma unroll
        for (int j=0;j<4;++j){ accA[i][j]=(f32x4)(0.f); accG[i][j]=(f32x4)(0.f); }

    // phase 1a: a-half (Wenc rows 0..511)
    stageA64(A, 512, n0, 0, &AL[0][0]);
    stageB512(W1, 512, 0, 0, &BL[0][0]);
    __syncthreads();
    for (int T=0; T<16; ++T){
        int buf = T & 1, nb = buf ^ 1;
        if (T+1 < 16){
            stageA64(A, 512, n0, (T+1)*32, &AL[nb][0]);
            stageB512(W1, 512, 0, (T+1)*32, &BL[nb][0]);
        }
        bf16x8 bf4[4];
        #pragma unroll
        for (int fn=0; fn<4; ++fn)
            bf4[fn] = *(const bf16x8*)&BL[buf][(w*64 + fn*16 + lrow)*32 + lcol];
        #pragma unroll
        for (int fm=0; fm<4; ++fm){
            bf16x8 af = *(const bf16x8*)&AL[buf][(fm*16 + lrow)*32 + lcol];
            #pragma unroll
            for (int fn=0; fn<4; ++fn)
                accA[fm][fn] = __builtin_amdgcn_mfma_f32_16x16x32_bf16(af, bf4[fn], accA[fm][fn], 0,0,0);
        }
        __syncthreads();
    }
    // phase 1b: g-half (Wenc rows 512..1023)
    stageA64(A, 512, n0, 0, &AL[0][0]);
    stageB512(W1, 512, 512, 0, &BL[0][0]);
    __syncthreads();
    for (int T=0; T<16; ++T){
        int buf = T & 1, nb = buf ^ 1;
        if (T+1 < 16){
            stageA64(A, 512, n0, (T+1)*32, &AL[nb][0]);
            stageB512(W1, 512, 512, (T+1)*32, &BL[nb][0]);
        }
        bf16x8 bf4[4];
        #pragma unroll
        for (int fn=0; fn<4; ++fn)
            bf4[fn] = *(const bf16x8*)&BL[buf][(w*64 + fn*16 + lrow)*32 + lcol];
        #pragma unroll
        for (int fm=0; fm<4; ++fm){
            bf16x8 af = *(const bf16x8*)&AL[buf][(fm*16 + lrow)*32 + lcol];
            #pragma unroll
            for (int fn=0; fn<4; ++fn)
                accG[fm][fn] = __builtin_amdgcn_mfma_f32_16x16x32_bf16(af, bf4[fn], accG[fm][fn], 0,0,0);
        }
        __syncthreads();
    }

    // GEGLU in-register -> FF LDS (T2 swizzle: granule ^= row&7)
    #pragma unroll
    for (int fm=0; fm<4; ++fm)
        #pragma unroll
        for (int fn=0; fn<4; ++fn)
            #pragma unroll
            for (int q=0; q<4; ++q){
                int row = fm*16 + er + q;
                int col = w*64 + fn*16 + ec;
                float ffv = accA[fm][fn][q] * gelu_exact(accG[fm][fn][q]);
                FF[row*512 + (((col >> 3) ^ (row & 7)) << 3) + (col & 7)] = f2b(ffv);
            }
    __syncthreads();

    // phase 2: out = FF @ Wdec^T  (A from LDS-resident FF)
    f32x4 accO[4][4];
    #pragma unroll
    for (int i=0;i<4;++i)
        #pragma unroll
        for (int j=0;j<4;++j) accO[i][j] = (f32x4)(0.f);
    stageB512(W2, 512, 0, 0, &BL[0][0]);
    __syncthreads();
    for (int T=0; T<16; ++T){
        int buf = T & 1, nb = buf ^ 1;
        if (T+1 < 16)
            stageB512(W2, 512, 0, (T+1)*32, &BL[nb][0]);
        bf16x8 bf4[4];
        #pragma unroll
        for (int fn=0; fn<4; ++fn)
            bf4[fn] = *(const bf16x8*)&BL[buf][(w*64 + fn*16 + lrow)*32 + lcol];
        #pragma unroll
        for (int fm=0; fm<4; ++fm){
            int row = fm*16 + lrow;
            int gr = (T*4 + (l >> 4)) ^ (l & 7);
            bf16x8 af = *(const bf16x8*)&FF[row*512 + (gr << 3)];
            #pragma unroll
            for (int fn=0; fn<4; ++fn)
                accO[fm][fn] = __builtin_amdgcn_mfma_f32_16x16x32_bf16(af, bf4[fn], accO[fm][fn], 0,0,0);
        }
        __syncthreads();
    }

    // epilogue: out f32 = accO + fx2 residual
    #pragma unroll
    for (int fm=0; fm<4; ++fm)
        #pragma unroll
        for (int fn=0; fn<4; ++fn)
            #pragma unroll
            for (int q=0; q<4; ++q){
                int n = n0 + fm*16 + er + q;
                int m = w*64 + fn*16 + ec;
                outF[(size_t)n*Hz + m] = accO[fm][fn][q] + b2f(A[(size_t)n*Hz + m]);
            }
}

// ---------------- scan (f folded in, bf16 I/O, f32 state) ----------------
__global__ __launch_bounds__(256) void scan_phase1(const u16* __restrict__ g,
                                                   const float* __restrict__ prm,
                                                   float* __restrict__ ERe,
                                                   float* __restrict__ EIm){
    int t = blockIdx.x;
    int pb = t & 1; t >>= 1;
    int c  = t % NC; t /= NC;
    int b  = t;
    int p  = pb*256 + threadIdx.x;
    size_t base = ((size_t)(b*Lz + c*CL))*1024 + p;
    float Ar = prm[p], Ai = prm[Pz+p];
    float fre = prm[2*Pz+p], fim = prm[3*Pz+p];
    float xr = 0.f, xi = 0.f;
    for (int ll = 0; ll < CL; ++ll) {
        float gr = b2f(g[base]), gi = b2f(g[base+512]);
        float br = fre*gr - fim*gi;
        float bi = fre*gi + fim*gr;
        float nr = Ar*xr - Ai*xi + br;
        float ni = Ar*xi + Ai*xr + bi;
        xr = nr; xi = ni;
        base += 1024;
    }
    size_t ci = ((size_t)(b*NC + c))*Pz + p;
    ERe[ci] = xr; EIm[ci] = xi;
}

__global__ __launch_bounds__(256) void scan_combine(const float* __restrict__ ERe,
                                                    const float* __restrict__ EIm,
                                                    const float* __restrict__ prm,
                                                    float* __restrict__ SinRe,
                                                    float* __restrict__ SinIm){
    int gt = blockIdx.x*256 + threadIdx.x;   // over B*P
    int b = gt / Pz, p = gt % Pz;
    float Ar = prm[4*Pz+p], Ai = prm[5*Pz+p];
    float Sr = 0.f, Si = 0.f;
    for (int c = 0; c < NC; ++c) {
        size_t idx = ((size_t)(b*NC + c))*Pz + p;
        SinRe[idx] = Sr; SinIm[idx] = Si;
        float er = ERe[idx], ei = EIm[idx];
        float nr = Ar*Sr - Ai*Si + er;
        float ni = Ar*Si + Ai*Sr + ei;
        Sr = nr; Si = ni;
    }
}

__global__ __launch_bounds__(256) void scan_phase2(u16* __restrict__ g,
                                                   const float* __restrict__ prm,
                                                   const float* __restrict__ SinRe,
                                                   const float* __restrict__ SinIm){
    int t = blockIdx.x;
    int pb = t & 1; t >>= 1;
    int c  = t % NC; t /= NC;
    int b  = t;
    int p  = pb*256 + threadIdx.x;
    size_t base = ((size_t)(b*Lz + c*CL))*1024 + p;
    size_t ci = ((size_t)(b*NC + c))*Pz + p;
    float Ar = prm[p], Ai = prm[Pz+p];
    float fre = prm[2*Pz+p], fim = prm[3*Pz+p];
    float xr = SinRe[ci], xi = SinIm[ci];
    for (int ll = 0; ll < CL; ++ll) {
        float gr = b2f(g[base]), gi = b2f(g[base+512]);
        float br = fre*gr - fim*gi;
        float bi = fre*gi + fim*gr;
        float nr = Ar*xr - Ai*xi + br;
        float ni = Ar*xi + Ai*xr + bi;
        xr = nr; xi = ni;
        g[base] = f2b(xr); g[base+512] = f2b(xi);
        base += 1024;
    }
}

extern "C" void kernel_launch(void* const* d_in, const int* in_sizes, int n_in,
                              void* d_out, int out_size, void* d_ws, size_t ws_size,
                              hipStream_t stream) {
    const float* x        = (const float*)d_in[0];
    const float* ln1_w    = (const float*)d_in[1];
    const float* ln1_b    = (const float*)d_in[2];
    const float* Lre      = (const float*)d_in[3];
    const float* Lim      = (const float*)d_in[4];
    const float* B_re     = (const float*)d_in[5];
    const float* B_im     = (const float*)d_in[6];
    const float* C_re     = (const float*)d_in[7];
    const float* C_im     = (const float*)d_in[8];
    const float* Dv       = (const float*)d_in[9];
    const float* log_step = (const float*)d_in[10];
    const float* ln2_w    = (const float*)d_in[11];
    const float* ln2_b    = (const float*)d_in[12];
    const float* W_enc    = (const float*)d_in[13];
    const float* W_dec    = (const float*)d_in[14];
    float* out = (float*)d_out;

    const size_t NH = (size_t)Nz*Hz;   // 8388608
    char* W = (char*)d_ws;
    u16*   fxb  = (u16*)  (W);                    // [N,512] bf16: fx
    u16*   g    = (u16*)  (W + NH*2);             // [N,1024] bf16: g -> xs
    u16*   fx2b = (u16*)  (W + NH*6);             // [N,512] bf16: fx2
    float* ERe  = (float*)(W + NH*8);
    float* EIm  = ERe + CS;
    float* SinRe= EIm + CS;
    float* SinIm= SinRe + CS;
    float* prm  = SinIm + CS;                     // 6*Pz f32
    u16*   Bcat = (u16*)(prm + 6*Pz);             // [1024,512]
    u16*   Ccat = Bcat + 1024*512;                // [512,1024]
    u16*   Wenc = Ccat + 512*1024;                // [1024,512]
    u16*   Wdec = Wenc + 1024*512;                // [512,512]

    setup_kernel<<<dim3(2), dim3(256), 0, stream>>>(Lre, Lim, log_step, prm);

    cvt_all<<<dim3(6*1024), dim3(256), 0, stream>>>(B_re, B_im, C_re, C_im, W_enc, W_dec,
                                                    Bcat, Ccat, Wenc, Wdec);

    // LN1: x -> fxb
    ln_kernel<<<dim3(Nz), dim3(256), 0, stream>>>(x, ln1_w, ln1_b, fxb);

    // GEMM1: g = fxb @ Bcat^T   grid 256, 1 block/CU
    gemm1_row<<<dim3(Nz/64), dim3(512), 0, stream>>>(fxb, Bcat, g);

    // scan: g -> xs in place
    scan_phase1<<<dim3(Bz*NC*2), dim3(256), 0, stream>>>(g, prm, ERe, EIm);
    scan_combine<<<dim3((Bz*Pz)/256), dim3(256), 0, stream>>>(ERe, EIm, prm, SinRe, SinIm);
    scan_phase2<<<dim3(Bz*NC*2), dim3(256), 0, stream>>>(g, prm, SinRe, SinIm);

    // GEMM2 + EY + LN2: fx2b
    gemm2_ln<<<dim3(Nz/64), dim3(512), 0, stream>>>(g, Ccat, fxb, Dv, ln2_w, ln2_b, fx2b);

    // MLP megakernel: out
    mlp_fused<<<dim3(Nz/64), dim3(512), 0, stream>>>(fx2b, Wenc, Wdec, out);
}

// Round 9
// 212.521 us; speedup vs baseline: 1.0744x; 1.0744x over previous
//
#include <hip/hip_runtime.h>
#include <math.h>

// (B,L,H,P) = (4,4096,512,512)
#define Bz 4
#define Lz 4096
#define Hz 512
#define Pz 512
#define Nz (Bz*Lz)          // 16384 rows
#define CL 64               // scan chunk length
#define NC (Lz/CL)          // 64 chunks
#define CS (Bz*NC*Pz)       // 131072 carry slots
#define EPSf 1e-5f

typedef unsigned short u16;
typedef unsigned int   u32;
typedef __attribute__((ext_vector_type(8))) short bf16x8;
typedef __attribute__((ext_vector_type(4))) float f32x4;

__device__ __forceinline__ float gelu_exact(float x){
    return 0.5f * x * (1.0f + erff(x * 0.70710678118654752f));
}
__device__ __forceinline__ u16 f2b(float f){
    union { float f; u32 u; } v; v.f = f;
    u32 u = v.u;
    u32 r = (u + 0x7FFFu + ((u >> 16) & 1u)) >> 16;   // RTNE
    return (u16)r;
}
__device__ __forceinline__ float b2f(u16 h){
    union { u32 u; float f; } v; v.u = ((u32)h) << 16; return v.f;
}
__device__ __forceinline__ float cvt_in(float x){ return x; }
__device__ __forceinline__ float cvt_in(u16 x){ return b2f(x); }

__device__ __forceinline__ void gload_lds16(const u16* g, u16* l){
    __builtin_amdgcn_global_load_lds(
        (const __attribute__((address_space(1))) void*)g,
        (__attribute__((address_space(3))) void*)l, 16, 0, 0);
}

// ---------------- setup: per-state SSM params ----------------
__global__ void setup_kernel(const float* __restrict__ Lre, const float* __restrict__ Lim,
                             const float* __restrict__ log_step,
                             float* __restrict__ prm){
    int p = blockIdx.x*blockDim.x + threadIdx.x;
    if (p >= Pz) return;
    float lr = Lre[p], li = Lim[p];
    float dt = expf(log_step[p]);
    float ar = lr*dt, ai = li*dt;
    float e = expf(ar);
    float Abr = e*cosf(ai), Abi = e*sinf(ai);   // Lambda_bar
    prm[p]        = Abr;
    prm[Pz + p]   = Abi;
    float nr = Abr - 1.0f, ni = Abi;
    float d2 = lr*lr + li*li;
    prm[2*Pz + p] = (nr*lr + ni*li)/d2;   // fRe
    prm[3*Pz + p] = (ni*lr - nr*li)/d2;   // fIm
    float arC = ar*(float)CL, aiC = ai*(float)CL;
    float eC = expf(arC);
    prm[4*Pz + p] = eC*cosf(aiC);         // ApowRe
    prm[5*Pz + p] = eC*sinf(aiC);         // ApowIm
}

// ---------------- merged weight converts (one launch) ----------------
__global__ __launch_bounds__(256) void cvt_all(const float* __restrict__ B_re,
                                               const float* __restrict__ B_im,
                                               const float* __restrict__ C_re,
                                               const float* __restrict__ C_im,
                                               const float* __restrict__ W_enc,
                                               const float* __restrict__ W_dec,
                                               u16* __restrict__ Bcat,
                                               u16* __restrict__ Ccat,
                                               u16* __restrict__ Wenc,
                                               u16* __restrict__ Wdec){
    const int Q = 512*512;
    int i = blockIdx.x*256 + threadIdx.x;
    if (i < Q){ Bcat[i] = f2b(B_re[i]); return; }
    i -= Q;
    if (i < Q){ Bcat[Q + i] = f2b(B_im[i]); return; }
    i -= Q;
    if (i < Q){
        int h = i >> 9, p = i & 511;
        Ccat[(size_t)h*1024 + p]       = f2b(C_re[i]);
        Ccat[(size_t)h*1024 + 512 + p] = f2b(-C_im[i]);
        return;
    }
    i -= Q;
    if (i < 2*Q){ Wenc[i] = f2b(W_enc[i]); return; }
    i -= 2*Q;
    Wdec[i] = f2b(W_dec[i]);
}

// ---------------- LayerNorm: (f32|bf16) in -> bf16 out ----------------
template<typename T>
__global__ __launch_bounds__(256) void ln_kernel(const T* __restrict__ in,
                                                 const float* __restrict__ w,
                                                 const float* __restrict__ b,
                                                 u16* __restrict__ ob){
    int row = blockIdx.x;
    int tid = threadIdx.x;
    const T* r = in + (size_t)row*Hz;
    float v0 = cvt_in(r[tid]), v1 = cvt_in(r[tid+256]);
    float s = v0+v1, q = v0*v0+v1*v1;
    #pragma unroll
    for (int o=32;o;o>>=1){ s += __shfl_down(s,o); q += __shfl_down(q,o); }
    __shared__ float ss[4], sq[4];
    __shared__ float mu_s, rs_s;
    int wid = tid>>6, lane = tid&63;
    if (lane==0){ ss[wid]=s; sq[wid]=q; }
    __syncthreads();
    if (tid==0){
        float S=ss[0]+ss[1]+ss[2]+ss[3];
        float Q=sq[0]+sq[1]+sq[2]+sq[3];
        float mu = S/(float)Hz;
        float var = Q/(float)Hz - mu*mu;
        mu_s = mu; rs_s = rsqrtf(var + EPSf);
    }
    __syncthreads();
    float mu = mu_s, rs = rs_s;
    u16* o = ob + (size_t)row*Hz;
    o[tid]     = f2b((v0-mu)*rs*w[tid]    +b[tid]);
    o[tid+256] = f2b((v1-mu)*rs*w[tid+256]+b[tid+256]);
}

// ============ 3-deep counted-vmcnt 128x128 MFMA GEMM ============
// C[N,M] = A[N,K] @ Bw[M,K]^T. BM=BN=128, BK=32, 256 threads (4 waves).
// Wave w: all 128 rows x cols [w*32,w*32+32) -> acc[8][2] f32x4.
// LDS: 3 buffers x (8KB A + 8KB B) = 48KB -> 3 blocks/CU.
// Pipeline: tiles T,T+1 staged in prologue. Per step:
//   s_waitcnt vmcnt(4)  (tile T's 4 loads/thread done; T+1's in flight)
//   s_barrier           (=> ALL waves' tile-T loads landed)
//   stage(T+2)          (4 more loads; vmcnt back to 8)
//   ds_read buf[T%3] + 16 MFMA
// vmcnt never drains to 0 mid-loop (T4 mechanism); HBM latency has ~2 steps
// of cover. WAR-safe: each wave's ds_reads drain (lgkm) before its MFMAs,
// which precede its next barrier; overwrite of buf[T%3] is issued at step
// T+1, after that barrier.
#define EB16 0
#define EY   1
#define ERES 2

// stage 128 rows x 32 cols bf16 (8KB); 2 gload_lds per thread (256 thr)
// R7-HW-verified 0-conflict swizzle pair with the reader below.
__device__ __forceinline__ void stage32(const u16* __restrict__ src, int ld,
                                        int grow0, int kt, u16* lds){
    int lane = threadIdx.x & 63;
    int w    = threadIdx.x >> 6;                       // 0..3
    #pragma unroll
    for (int q = 0; q < 2; ++q){
        int c = w + q*4;                               // 1KB chunk, 0..7 (16 rows)
        int r = c*16 + (lane >> 2);                    // row 0..127
        int colE = 8*((lane & 3) ^ ((lane >> 3) & 3)); // swizzled source granule
        const u16* g = src + (size_t)(grow0 + r)*ld + kt + colE;
        gload_lds16(g, lds + c*512);                   // wave-uniform base + lane*16B
    }
}

template<int K, int EPI>
__global__ __launch_bounds__(256, 3)
void gemm3b(const u16* __restrict__ A, const u16* __restrict__ Bw, int M,
            u16* __restrict__ outB,
            const u16* __restrict__ fxB,        // EY: bf16 residual fx
            const float* __restrict__ Dv,       // EY
            const u16* __restrict__ resB,       // ERES
            float* __restrict__ outF)           // ERES
{
    constexpr int NT = K/32;
    __shared__ u16 AL[3][128*32];
    __shared__ u16 BL[3][128*32];

    // XCD-aware bijective swizzle (nwg % 8 == 0 for all our grids)
    int nx = gridDim.x, ny = gridDim.y;
    int nwg = nx*ny;
    int lid = blockIdx.x + blockIdx.y*nx;
    int cpx = nwg >> 3;
    int gdx = (lid & 7)*cpx + (lid >> 3);
    int n0 = (gdx / ny) * 128;
    int m0 = (gdx % ny) * 128;

    int l = threadIdx.x & 63;
    int w = threadIdx.x >> 6;
    int lrow = l & 15;
    int lcol = 8*((l >> 4) ^ ((l >> 1) & 3));   // swizzled u16 col in 32-col row
    int colw = w*32;

    f32x4 acc[8][2];
    #pragma unroll
    for (int i=0;i<8;++i){ acc[i][0]=(f32x4)(0.f); acc[i][1]=(f32x4)(0.f); }

    // prologue: stage tiles 0 and 1 (8 loads/thread outstanding)
    stage32(A,  K, n0, 0,  &AL[0][0]);
    stage32(Bw, K, m0, 0,  &BL[0][0]);
    stage32(A,  K, n0, 32, &AL[1][0]);
    stage32(Bw, K, m0, 32, &BL[1][0]);

    for (int T=0; T<NT; ++T){
        if (T == NT-1){ asm volatile("s_waitcnt vmcnt(0)" ::: "memory"); }
        else          { asm volatile("s_waitcnt vmcnt(4)" ::: "memory"); }
        __builtin_amdgcn_s_barrier();
        __builtin_amdgcn_sched_barrier(0);
        if (T+2 < NT){
            int bs = T+2; bs -= (bs>=3)?3:0; bs -= (bs>=3)?3:0;  // (T+2)%3 cheap
            // recompute properly: T+2 mod 3
            bs = (T+2)%3;
            stage32(A,  K, n0, (T+2)*32, &AL[bs][0]);
            stage32(Bw, K, m0, (T+2)*32, &BL[bs][0]);
        }
        const u16* Ab = &AL[T%3][0];
        const u16* Bb = &BL[T%3][0];
        bf16x8 bfr[2];
        #pragma unroll
        for (int fn=0; fn<2; ++fn)
            bfr[fn] = *(const bf16x8*)&Bb[(colw + fn*16 + lrow)*32 + lcol];
        #pragma unroll
        for (int f=0; f<8; ++f){
            bf16x8 af = *(const bf16x8*)&Ab[(f*16 + lrow)*32 + lcol];
            #pragma unroll
            for (int fn=0; fn<2; ++fn)
                acc[f][fn] = __builtin_amdgcn_mfma_f32_16x16x32_bf16(af, bfr[fn], acc[f][fn], 0,0,0);
        }
    }

    // epilogue: C layout col=lane&15, row=(lane>>4)*4+q
    int er = (l >> 4) * 4;
    int ec = l & 15;
    #pragma unroll
    for (int fm=0; fm<8; ++fm)
        #pragma unroll
        for (int fn=0; fn<2; ++fn)
            #pragma unroll
            for (int q=0; q<4; ++q){
                int n = n0 + fm*16 + er + q;
                int m = m0 + colw + fn*16 + ec;
                float v = acc[fm][fn][q];
                if (EPI == EB16){
                    outB[(size_t)n*M + m] = f2b(v);
                } else if (EPI == EY){
                    size_t idx = (size_t)n*Hz + m;
                    float fxv = b2f(fxB[idx]);
                    float y = 2.0f*v + Dv[m]*fxv;
                    outB[idx] = f2b(gelu_exact(y) + fxv);
                } else {
                    size_t idx = (size_t)n*Hz + m;
                    outF[idx] = v + b2f(resB[idx]);
                }
            }
}

// ---------------- scan (f folded in, bf16 I/O, f32 state) ----------------
// g layout: [N][1024], cols [0,512)=Re raw, [512,1024)=Im raw
__global__ __launch_bounds__(256) void scan_phase1(const u16* __restrict__ g,
                                                   const float* __restrict__ prm,
                                                   float* __restrict__ ERe,
                                                   float* __restrict__ EIm){
    int t = blockIdx.x;
    int pb = t & 1; t >>= 1;
    int c  = t % NC; t /= NC;
    int b  = t;
    int p  = pb*256 + threadIdx.x;
    size_t base = ((size_t)(b*Lz + c*CL))*1024 + p;
    float Ar = prm[p], Ai = prm[Pz+p];
    float fre = prm[2*Pz+p], fim = prm[3*Pz+p];
    float xr = 0.f, xi = 0.f;
    for (int ll = 0; ll < CL; ++ll) {
        float gr = b2f(g[base]), gi = b2f(g[base+512]);
        float br = fre*gr - fim*gi;
        float bi = fre*gi + fim*gr;
        float nr = Ar*xr - Ai*xi + br;
        float ni = Ar*xi + Ai*xr + bi;
        xr = nr; xi = ni;
        base += 1024;
    }
    size_t ci = ((size_t)(b*NC + c))*Pz + p;
    ERe[ci] = xr; EIm[ci] = xi;
}

__global__ __launch_bounds__(256) void scan_combine(const float* __restrict__ ERe,
                                                    const float* __restrict__ EIm,
                                                    const float* __restrict__ prm,
                                                    float* __restrict__ SinRe,
                                                    float* __restrict__ SinIm){
    int gt = blockIdx.x*256 + threadIdx.x;   // over B*P
    int b = gt / Pz, p = gt % Pz;
    float Ar = prm[4*Pz+p], Ai = prm[5*Pz+p];
    float Sr = 0.f, Si = 0.f;
    for (int c = 0; c < NC; ++c) {
        size_t idx = ((size_t)(b*NC + c))*Pz + p;
        SinRe[idx] = Sr; SinIm[idx] = Si;
        float er = ERe[idx], ei = EIm[idx];
        float nr = Ar*Sr - Ai*Si + er;
        float ni = Ar*Si + Ai*Sr + ei;
        Sr = nr; Si = ni;
    }
}

// overwrites g with xs (bf16, same [re|im] layout)
__global__ __launch_bounds__(256) void scan_phase2(u16* __restrict__ g,
                                                   const float* __restrict__ prm,
                                                   const float* __restrict__ SinRe,
                                                   const float* __restrict__ SinIm){
    int t = blockIdx.x;
    int pb = t & 1; t >>= 1;
    int c  = t % NC; t /= NC;
    int b  = t;
    int p  = pb*256 + threadIdx.x;
    size_t base = ((size_t)(b*Lz + c*CL))*1024 + p;
    size_t ci = ((size_t)(b*NC + c))*Pz + p;
    float Ar = prm[p], Ai = prm[Pz+p];
    float fre = prm[2*Pz+p], fim = prm[3*Pz+p];
    float xr = SinRe[ci], xi = SinIm[ci];
    for (int ll = 0; ll < CL; ++ll) {
        float gr = b2f(g[base]), gi = b2f(g[base+512]);
        float br = fre*gr - fim*gi;
        float bi = fre*gi + fim*gr;
        float nr = Ar*xr - Ai*xi + br;
        float ni = Ar*xi + Ai*xr + bi;
        xr = nr; xi = ni;
        g[base] = f2b(xr); g[base+512] = f2b(xi);
        base += 1024;
    }
}

// ---------------- GEGLU elementwise: ff = a * gelu(g) ----------------
__global__ __launch_bounds__(256) void geglu_kernel(const u16* __restrict__ e,
                                                    u16* __restrict__ ff){
    size_t i = (size_t)blockIdx.x*256 + threadIdx.x;  // over N*512
    int n = (int)(i >> 9), m = (int)(i & 511);
    float a = b2f(e[(size_t)n*1024 + m]);
    float gg = b2f(e[(size_t)n*1024 + 512 + m]);
    ff[i] = f2b(a * gelu_exact(gg));
}

extern "C" void kernel_launch(void* const* d_in, const int* in_sizes, int n_in,
                              void* d_out, int out_size, void* d_ws, size_t ws_size,
                              hipStream_t stream) {
    const float* x        = (const float*)d_in[0];
    const float* ln1_w    = (const float*)d_in[1];
    const float* ln1_b    = (const float*)d_in[2];
    const float* Lre      = (const float*)d_in[3];
    const float* Lim      = (const float*)d_in[4];
    const float* B_re     = (const float*)d_in[5];
    const float* B_im     = (const float*)d_in[6];
    const float* C_re     = (const float*)d_in[7];
    const float* C_im     = (const float*)d_in[8];
    const float* Dv       = (const float*)d_in[9];
    const float* log_step = (const float*)d_in[10];
    const float* ln2_w    = (const float*)d_in[11];
    const float* ln2_b    = (const float*)d_in[12];
    const float* W_enc    = (const float*)d_in[13];
    const float* W_dec    = (const float*)d_in[14];
    float* out = (float*)d_out;

    const size_t NH = (size_t)Nz*Hz;   // 8388608
    char* W = (char*)d_ws;
    u16*   fxb  = (u16*)  (W);                    // [N,512] bf16: fx, later ff
    u16*   g    = (u16*)  (W + NH*2);             // [N,1024] bf16: g -> xs -> e
    u16*   hb   = (u16*)  (W + NH*6);             // [N,512] bf16: h
    u16*   fx2b = (u16*)  (W + NH*8);             // [N,512] bf16: fx2
    float* ERe  = (float*)(W + NH*10);
    float* EIm  = ERe + CS;
    float* SinRe= EIm + CS;
    float* SinIm= SinRe + CS;
    float* prm  = SinIm + CS;                     // 6*Pz f32
    u16*   Bcat = (u16*)(prm + 6*Pz);             // [1024,512]
    u16*   Ccat = Bcat + 1024*512;                // [512,1024]
    u16*   Wenc = Ccat + 512*1024;                // [1024,512]
    u16*   Wdec = Wenc + 1024*512;                // [512,512]

    setup_kernel<<<dim3(2), dim3(256), 0, stream>>>(Lre, Lim, log_step, prm);

    cvt_all<<<dim3(6*1024), dim3(256), 0, stream>>>(B_re, B_im, C_re, C_im, W_enc, W_dec,
                                                    Bcat, Ccat, Wenc, Wdec);

    // LN1: x -> fxb (bf16)
    ln_kernel<float><<<dim3(Nz), dim3(256), 0, stream>>>(x, ln1_w, ln1_b, fxb);

    // GEMM1: g = fxb @ Bcat^T   [N,1024]   grid 128x8 = 1024 blocks
    gemm3b<512,EB16><<<dim3(Nz/128, 1024/128), dim3(256), 0, stream>>>(
        fxb, Bcat, 1024, g, nullptr, nullptr, nullptr, nullptr);

    // scan: g (raw) -> xs (in place), f-scaling applied on load
    scan_phase1<<<dim3(Bz*NC*2), dim3(256), 0, stream>>>(g, prm, ERe, EIm);
    scan_combine<<<dim3((Bz*Pz)/256), dim3(256), 0, stream>>>(ERe, EIm, prm, SinRe, SinIm);
    scan_phase2<<<dim3(Bz*NC*2), dim3(256), 0, stream>>>(g, prm, SinRe, SinIm);

    // GEMM2 (Y): h = gelu(2*(xs@Ccat^T) + D*fx) + fx -> hb   grid 128x4
    gemm3b<1024,EY><<<dim3(Nz/128, 512/128), dim3(256), 0, stream>>>(
        g, Ccat, 512, hb, fxb, Dv, nullptr, nullptr);

    // LN2: hb -> fx2b (bf16)
    ln_kernel<u16><<<dim3(Nz), dim3(256), 0, stream>>>(hb, ln2_w, ln2_b, fx2b);

    // GEMM3: e = fx2b @ Wenc^T  [N,1024]  grid 128x8
    gemm3b<512,EB16><<<dim3(Nz/128, 1024/128), dim3(256), 0, stream>>>(
        fx2b, Wenc, 1024, g, nullptr, nullptr, nullptr, nullptr);

    // GEGLU: ff = a * gelu(gg)  (over fxb slot)
    geglu_kernel<<<dim3((unsigned)(NH/256)), dim3(256), 0, stream>>>(g, fxb);

    // GEMM4: out = ff @ Wdec^T + fx2   grid 128x4
    gemm3b<512,ERES><<<dim3(Nz/128, 512/128), dim3(256), 0, stream>>>(
        fxb, Wdec, 512, nullptr, nullptr, nullptr, fx2b, out);
}

// Round 10
// 201.314 us; speedup vs baseline: 1.1342x; 1.0557x over previous
//
#include <hip/hip_runtime.h>
#include <math.h>

// (B,L,H,P) = (4,4096,512,512)
#define Bz 4
#define Lz 4096
#define Hz 512
#define Pz 512
#define Nz (Bz*Lz)          // 16384 rows
#define CL 64               // scan chunk length
#define NC (Lz/CL)          // 64 chunks
#define CS (Bz*NC*Pz)       // 131072 carry slots
#define EPSf 1e-5f

typedef unsigned short u16;
typedef unsigned int   u32;
typedef __attribute__((ext_vector_type(8))) short bf16x8;
typedef __attribute__((ext_vector_type(4))) float f32x4;

__device__ __forceinline__ float gelu_exact(float x){
    return 0.5f * x * (1.0f + erff(x * 0.70710678118654752f));
}
__device__ __forceinline__ u16 f2b(float f){
    union { float f; u32 u; } v; v.f = f;
    u32 u = v.u;
    u32 r = (u + 0x7FFFu + ((u >> 16) & 1u)) >> 16;   // RTNE
    return (u16)r;
}
__device__ __forceinline__ float b2f(u16 h){
    union { u32 u; float f; } v; v.u = ((u32)h) << 16; return v.f;
}
__device__ __forceinline__ float cvt_in(float x){ return x; }
__device__ __forceinline__ float cvt_in(u16 x){ return b2f(x); }

__device__ __forceinline__ void gload_lds16(const u16* g, u16* l){
    __builtin_amdgcn_global_load_lds(
        (const __attribute__((address_space(1))) void*)g,
        (__attribute__((address_space(3))) void*)l, 16, 0, 0);
}

// ---------------- setup: per-state SSM params ----------------
__global__ void setup_kernel(const float* __restrict__ Lre, const float* __restrict__ Lim,
                             const float* __restrict__ log_step,
                             float* __restrict__ prm){
    int p = blockIdx.x*blockDim.x + threadIdx.x;
    if (p >= Pz) return;
    float lr = Lre[p], li = Lim[p];
    float dt = expf(log_step[p]);
    float ar = lr*dt, ai = li*dt;
    float e = expf(ar);
    float Abr = e*cosf(ai), Abi = e*sinf(ai);   // Lambda_bar
    prm[p]        = Abr;
    prm[Pz + p]   = Abi;
    float nr = Abr - 1.0f, ni = Abi;
    float d2 = lr*lr + li*li;
    prm[2*Pz + p] = (nr*lr + ni*li)/d2;   // fRe
    prm[3*Pz + p] = (ni*lr - nr*li)/d2;   // fIm
    float arC = ar*(float)CL, aiC = ai*(float)CL;
    float eC = expf(arC);
    prm[4*Pz + p] = eC*cosf(aiC);         // ApowRe
    prm[5*Pz + p] = eC*sinf(aiC);         // ApowIm
}

// ---------------- merged weight converts (one launch) ----------------
__global__ __launch_bounds__(256) void cvt_all(const float* __restrict__ B_re,
                                               const float* __restrict__ B_im,
                                               const float* __restrict__ C_re,
                                               const float* __restrict__ C_im,
                                               const float* __restrict__ W_enc,
                                               const float* __restrict__ W_dec,
                                               u16* __restrict__ Bcat,
                                               u16* __restrict__ Ccat,
                                               u16* __restrict__ Wenc,
                                               u16* __restrict__ Wdec){
    const int Q = 512*512;
    int i = blockIdx.x*256 + threadIdx.x;
    if (i < Q){ Bcat[i] = f2b(B_re[i]); return; }
    i -= Q;
    if (i < Q){ Bcat[Q + i] = f2b(B_im[i]); return; }
    i -= Q;
    if (i < Q){
        int h = i >> 9, p = i & 511;
        Ccat[(size_t)h*1024 + p]       = f2b(C_re[i]);
        Ccat[(size_t)h*1024 + 512 + p] = f2b(-C_im[i]);
        return;
    }
    i -= Q;
    if (i < 2*Q){ Wenc[i] = f2b(W_enc[i]); return; }
    i -= 2*Q;
    Wdec[i] = f2b(W_dec[i]);
}

// ---------------- LayerNorm: (f32|bf16) in -> bf16 out ----------------
template<typename T>
__global__ __launch_bounds__(256) void ln_kernel(const T* __restrict__ in,
                                                 const float* __restrict__ w,
                                                 const float* __restrict__ b,
                                                 u16* __restrict__ ob){
    int row = blockIdx.x;
    int tid = threadIdx.x;
    const T* r = in + (size_t)row*Hz;
    float v0 = cvt_in(r[tid]), v1 = cvt_in(r[tid+256]);
    float s = v0+v1, q = v0*v0+v1*v1;
    #pragma unroll
    for (int o=32;o;o>>=1){ s += __shfl_down(s,o); q += __shfl_down(q,o); }
    __shared__ float ss[4], sq[4];
    __shared__ float mu_s, rs_s;
    int wid = tid>>6, lane = tid&63;
    if (lane==0){ ss[wid]=s; sq[wid]=q; }
    __syncthreads();
    if (tid==0){
        float S=ss[0]+ss[1]+ss[2]+ss[3];
        float Q=sq[0]+sq[1]+sq[2]+sq[3];
        float mu = S/(float)Hz;
        float var = Q/(float)Hz - mu*mu;
        mu_s = mu; rs_s = rsqrtf(var + EPSf);
    }
    __syncthreads();
    float mu = mu_s, rs = rs_s;
    u16* o = ob + (size_t)row*Hz;
    o[tid]     = f2b((v0-mu)*rs*w[tid]    +b[tid]);
    o[tid+256] = f2b((v1-mu)*rs*w[tid+256]+b[tid+256]);
}

// ============ 8-wave 256x128 MFMA GEMM (4 waves/SIMD when 2 blocks/CU) ============
// C[N,M] = A[N,K] @ Bw[M,K]^T. BM=256, BN=128, BK=32, 512 threads (8 waves).
// Wave w = (wr=w>>1, wc=w&1) owns a 64x64 sub-tile: acc[4][4] f32x4 (64 VGPR),
// 8 ds_read_b128 + 16 MFMA per K-step == m97's proven per-wave shape.
// LDS: 2 x (A 16KB + B 8KB) = 48KB; __launch_bounds__(512,4) -> VGPR<=128 ->
// 2 blocks/CU co-resident = 4 waves/SIMD: the TLP that hides ds_read/MFMA
// latency (m114); all prior rounds ran ~1.5 waves/SIMD effective.
// Swizzle (R7 HW-verified, SQ_LDS_BANK_CONFLICT=0): stage source granule
// colE = 8*((lane&3)^((lane>>3)&3)); reader lcol = 8*((l>>4)^((l>>1)&3)).
#define EB16 0
#define EY   1
#define ERES 2

// stage [256][32] bf16 (16KB), 512 threads x 2 loads
__device__ __forceinline__ void stageA256(const u16* __restrict__ src, int ld,
                                          int row0, int kt, u16* lds){
    int lane = threadIdx.x & 63, w = threadIdx.x >> 6;
    #pragma unroll
    for (int q = 0; q < 2; ++q){
        int c = w + q*8;                               // 1KB chunk, 0..15 (16 rows)
        int r = c*16 + (lane >> 2);                    // row 0..255
        int colE = 8*((lane & 3) ^ ((lane >> 3) & 3));
        gload_lds16(src + (size_t)(row0 + r)*ld + kt + colE, lds + c*512);
    }
}
// stage [128][32] bf16 (8KB), 512 threads x 1 load
__device__ __forceinline__ void stageB128(const u16* __restrict__ src, int ld,
                                          int row0, int kt, u16* lds){
    int lane = threadIdx.x & 63, w = threadIdx.x >> 6; // w 0..7 = chunk
    int r = w*16 + (lane >> 2);                        // row 0..127
    int colE = 8*((lane & 3) ^ ((lane >> 3) & 3));
    gload_lds16(src + (size_t)(row0 + r)*ld + kt + colE, lds + w*512);
}

template<int K, int EPI>
__global__ __launch_bounds__(512, 4)
void gemmw(const u16* __restrict__ A, const u16* __restrict__ Bw, int M,
           u16* __restrict__ outB,
           const u16* __restrict__ fxB,        // EY: bf16 residual fx
           const float* __restrict__ Dv,       // EY
           const u16* __restrict__ resB,       // ERES
           float* __restrict__ outF)           // ERES
{
    constexpr int NT = K/32;
    __shared__ u16 AL[2][256*32];   // 2 x 16KB
    __shared__ u16 BL[2][128*32];   // 2 x 8KB

    // XCD-aware bijective swizzle (nwg % 8 == 0 for all our grids)
    int nx = gridDim.x, ny = gridDim.y;
    int nwg = nx*ny;
    int lid = blockIdx.x + blockIdx.y*nx;
    int cpx = nwg >> 3;
    int gdx = (lid & 7)*cpx + (lid >> 3);
    int n0 = (gdx / ny) * 256;
    int m0 = (gdx % ny) * 128;

    int l = threadIdx.x & 63;
    int w = threadIdx.x >> 6;
    int wr = w >> 1, wc = w & 1;
    int rbase = wr*64, cbase = wc*64;
    int lrow = l & 15;
    int lcol = 8*((l >> 4) ^ ((l >> 1) & 3));   // swizzled u16 col in 32-col row

    f32x4 acc[4][4];
    #pragma unroll
    for (int i=0;i<4;++i)
        #pragma unroll
        for (int j=0;j<4;++j) acc[i][j] = (f32x4)(0.f);

    // prologue: stage tile 0
    stageA256(A,  K, n0, 0, &AL[0][0]);
    stageB128(Bw, K, m0, 0, &BL[0][0]);
    __syncthreads();

    for (int T=0; T<NT; ++T){
        int buf = T & 1, nb = buf ^ 1;
        if (T+1 < NT){
            int ktn = (T+1)*32;
            stageA256(A,  K, n0, ktn, &AL[nb][0]);
            stageB128(Bw, K, m0, ktn, &BL[nb][0]);
        }
        const u16* Ab = &AL[buf][0];
        const u16* Bb = &BL[buf][0];
        bf16x8 bf4[4];
        #pragma unroll
        for (int fn=0; fn<4; ++fn)
            bf4[fn] = *(const bf16x8*)&Bb[(cbase + fn*16 + lrow)*32 + lcol];
        #pragma unroll
        for (int fm=0; fm<4; ++fm){
            bf16x8 af = *(const bf16x8*)&Ab[(rbase + fm*16 + lrow)*32 + lcol];
            #pragma unroll
            for (int fn=0; fn<4; ++fn)
                acc[fm][fn] = __builtin_amdgcn_mfma_f32_16x16x32_bf16(af, bf4[fn], acc[fm][fn], 0,0,0);
        }
        __syncthreads();   // staged tile landed (vmcnt0) + WAR protection
    }

    // epilogue: C layout col=lane&15, row=(lane>>4)*4+q
    int er = (l >> 4) * 4;
    int ec = l & 15;
    #pragma unroll
    for (int fm=0; fm<4; ++fm)
        #pragma unroll
        for (int fn=0; fn<4; ++fn)
            #pragma unroll
            for (int q=0; q<4; ++q){
                int n = n0 + rbase + fm*16 + er + q;
                int m = m0 + cbase + fn*16 + ec;
                float v = acc[fm][fn][q];
                if (EPI == EB16){
                    outB[(size_t)n*M + m] = f2b(v);
                } else if (EPI == EY){
                    size_t idx = (size_t)n*Hz + m;
                    float fxv = b2f(fxB[idx]);
                    float y = 2.0f*v + Dv[m]*fxv;
                    outB[idx] = f2b(gelu_exact(y) + fxv);
                } else {
                    size_t idx = (size_t)n*Hz + m;
                    outF[idx] = v + b2f(resB[idx]);
                }
            }
}

// ---------------- scan (f folded in, bf16 I/O, f32 state) ----------------
// g layout: [N][1024], cols [0,512)=Re raw, [512,1024)=Im raw
__global__ __launch_bounds__(256) void scan_phase1(const u16* __restrict__ g,
                                                   const float* __restrict__ prm,
                                                   float* __restrict__ ERe,
                                                   float* __restrict__ EIm){
    int t = blockIdx.x;
    int pb = t & 1; t >>= 1;
    int c  = t % NC; t /= NC;
    int b  = t;
    int p  = pb*256 + threadIdx.x;
    size_t base = ((size_t)(b*Lz + c*CL))*1024 + p;
    float Ar = prm[p], Ai = prm[Pz+p];
    float fre = prm[2*Pz+p], fim = prm[3*Pz+p];
    float xr = 0.f, xi = 0.f;
    for (int ll = 0; ll < CL; ++ll) {
        float gr = b2f(g[base]), gi = b2f(g[base+512]);
        float br = fre*gr - fim*gi;
        float bi = fre*gi + fim*gr;
        float nr = Ar*xr - Ai*xi + br;
        float ni = Ar*xi + Ai*xr + bi;
        xr = nr; xi = ni;
        base += 1024;
    }
    size_t ci = ((size_t)(b*NC + c))*Pz + p;
    ERe[ci] = xr; EIm[ci] = xi;
}

__global__ __launch_bounds__(256) void scan_combine(const float* __restrict__ ERe,
                                                    const float* __restrict__ EIm,
                                                    const float* __restrict__ prm,
                                                    float* __restrict__ SinRe,
                                                    float* __restrict__ SinIm){
    int gt = blockIdx.x*256 + threadIdx.x;   // over B*P
    int b = gt / Pz, p = gt % Pz;
    float Ar = prm[4*Pz+p], Ai = prm[5*Pz+p];
    float Sr = 0.f, Si = 0.f;
    for (int c = 0; c < NC; ++c) {
        size_t idx = ((size_t)(b*NC + c))*Pz + p;
        SinRe[idx] = Sr; SinIm[idx] = Si;
        float er = ERe[idx], ei = EIm[idx];
        float nr = Ar*Sr - Ai*Si + er;
        float ni = Ar*Si + Ai*Sr + ei;
        Sr = nr; Si = ni;
    }
}

// overwrites g with xs (bf16, same [re|im] layout)
__global__ __launch_bounds__(256) void scan_phase2(u16* __restrict__ g,
                                                   const float* __restrict__ prm,
                                                   const float* __restrict__ SinRe,
                                                   const float* __restrict__ SinIm){
    int t = blockIdx.x;
    int pb = t & 1; t >>= 1;
    int c  = t % NC; t /= NC;
    int b  = t;
    int p  = pb*256 + threadIdx.x;
    size_t base = ((size_t)(b*Lz + c*CL))*1024 + p;
    size_t ci = ((size_t)(b*NC + c))*Pz + p;
    float Ar = prm[p], Ai = prm[Pz+p];
    float fre = prm[2*Pz+p], fim = prm[3*Pz+p];
    float xr = SinRe[ci], xi = SinIm[ci];
    for (int ll = 0; ll < CL; ++ll) {
        float gr = b2f(g[base]), gi = b2f(g[base+512]);
        float br = fre*gr - fim*gi;
        float bi = fre*gi + fim*gr;
        float nr = Ar*xr - Ai*xi + br;
        float ni = Ar*xi + Ai*xr + bi;
        xr = nr; xi = ni;
        g[base] = f2b(xr); g[base+512] = f2b(xi);
        base += 1024;
    }
}

// ---------------- GEGLU elementwise: ff = a * gelu(g) ----------------
__global__ __launch_bounds__(256) void geglu_kernel(const u16* __restrict__ e,
                                                    u16* __restrict__ ff){
    size_t i = (size_t)blockIdx.x*256 + threadIdx.x;  // over N*512
    int n = (int)(i >> 9), m = (int)(i & 511);
    float a = b2f(e[(size_t)n*1024 + m]);
    float gg = b2f(e[(size_t)n*1024 + 512 + m]);
    ff[i] = f2b(a * gelu_exact(gg));
}

extern "C" void kernel_launch(void* const* d_in, const int* in_sizes, int n_in,
                              void* d_out, int out_size, void* d_ws, size_t ws_size,
                              hipStream_t stream) {
    const float* x        = (const float*)d_in[0];
    const float* ln1_w    = (const float*)d_in[1];
    const float* ln1_b    = (const float*)d_in[2];
    const float* Lre      = (const float*)d_in[3];
    const float* Lim      = (const float*)d_in[4];
    const float* B_re     = (const float*)d_in[5];
    const float* B_im     = (const float*)d_in[6];
    const float* C_re     = (const float*)d_in[7];
    const float* C_im     = (const float*)d_in[8];
    const float* Dv       = (const float*)d_in[9];
    const float* log_step = (const float*)d_in[10];
    const float* ln2_w    = (const float*)d_in[11];
    const float* ln2_b    = (const float*)d_in[12];
    const float* W_enc    = (const float*)d_in[13];
    const float* W_dec    = (const float*)d_in[14];
    float* out = (float*)d_out;

    const size_t NH = (size_t)Nz*Hz;   // 8388608
    char* W = (char*)d_ws;
    u16*   fxb  = (u16*)  (W);                    // [N,512] bf16: fx, later ff
    u16*   g    = (u16*)  (W + NH*2);             // [N,1024] bf16: g -> xs -> e
    u16*   hb   = (u16*)  (W + NH*6);             // [N,512] bf16: h
    u16*   fx2b = (u16*)  (W + NH*8);             // [N,512] bf16: fx2
    float* ERe  = (float*)(W + NH*10);
    float* EIm  = ERe + CS;
    float* SinRe= EIm + CS;
    float* SinIm= SinRe + CS;
    float* prm  = SinIm + CS;                     // 6*Pz f32
    u16*   Bcat = (u16*)(prm + 6*Pz);             // [1024,512]
    u16*   Ccat = Bcat + 1024*512;                // [512,1024]
    u16*   Wenc = Ccat + 512*1024;                // [1024,512]
    u16*   Wdec = Wenc + 1024*512;                // [512,512]

    setup_kernel<<<dim3(2), dim3(256), 0, stream>>>(Lre, Lim, log_step, prm);

    cvt_all<<<dim3(6*1024), dim3(256), 0, stream>>>(B_re, B_im, C_re, C_im, W_enc, W_dec,
                                                    Bcat, Ccat, Wenc, Wdec);

    // LN1: x -> fxb (bf16)
    ln_kernel<float><<<dim3(Nz), dim3(256), 0, stream>>>(x, ln1_w, ln1_b, fxb);

    // GEMM1: g = fxb @ Bcat^T   [N,1024]   grid 64x8 = 512 blocks, 2/CU
    gemmw<512,EB16><<<dim3(Nz/256, 1024/128), dim3(512), 0, stream>>>(
        fxb, Bcat, 1024, g, nullptr, nullptr, nullptr, nullptr);

    // scan: g (raw) -> xs (in place), f-scaling applied on load
    scan_phase1<<<dim3(Bz*NC*2), dim3(256), 0, stream>>>(g, prm, ERe, EIm);
    scan_combine<<<dim3((Bz*Pz)/256), dim3(256), 0, stream>>>(ERe, EIm, prm, SinRe, SinIm);
    scan_phase2<<<dim3(Bz*NC*2), dim3(256), 0, stream>>>(g, prm, SinRe, SinIm);

    // GEMM2 (Y): h = gelu(2*(xs@Ccat^T) + D*fx) + fx -> hb   grid 64x4 = 256
    gemmw<1024,EY><<<dim3(Nz/256, 512/128), dim3(512), 0, stream>>>(
        g, Ccat, 512, hb, fxb, Dv, nullptr, nullptr);

    // LN2: hb -> fx2b (bf16)
    ln_kernel<u16><<<dim3(Nz), dim3(256), 0, stream>>>(hb, ln2_w, ln2_b, fx2b);

    // GEMM3: e = fx2b @ Wenc^T  [N,1024]  grid 64x8 = 512
    gemmw<512,EB16><<<dim3(Nz/256, 1024/128), dim3(512), 0, stream>>>(
        fx2b, Wenc, 1024, g, nullptr, nullptr, nullptr, nullptr);

    // GEGLU: ff = a * gelu(gg)  (over fxb slot)
    geglu_kernel<<<dim3((unsigned)(NH/256)), dim3(256), 0, stream>>>(g, fxb);

    // GEMM4: out = ff @ Wdec^T + fx2   grid 64x4 = 256
    gemmw<512,ERES><<<dim3(Nz/256, 512/128), dim3(512), 0, stream>>>(
        fxb, Wdec, 512, nullptr, nullptr, nullptr, fx2b, out);
}

// Round 11
// 189.664 us; speedup vs baseline: 1.2038x; 1.0614x over previous
//
#include <hip/hip_runtime.h>
#include <math.h>

// (B,L,H,P) = (4,4096,512,512)
#define Bz 4
#define Lz 4096
#define Hz 512
#define Pz 512
#define Nz (Bz*Lz)          // 16384 rows
#define CL 64               // scan chunk length
#define NC (Lz/CL)          // 64 chunks
#define CS (Bz*NC*Pz)       // 131072 carry slots
#define EPSf 1e-5f

typedef unsigned short u16;
typedef unsigned int   u32;
typedef __attribute__((ext_vector_type(8))) short bf16x8;
typedef __attribute__((ext_vector_type(8))) short short8v;
typedef __attribute__((ext_vector_type(4))) short short4v;
typedef __attribute__((ext_vector_type(4))) float f32x4;

__device__ __forceinline__ float gelu_exact(float x){
    return 0.5f * x * (1.0f + erff(x * 0.70710678118654752f));
}
__device__ __forceinline__ u16 f2b(float f){
    union { float f; u32 u; } v; v.f = f;
    u32 u = v.u;
    u32 r = (u + 0x7FFFu + ((u >> 16) & 1u)) >> 16;   // RTNE
    return (u16)r;
}
__device__ __forceinline__ float b2f(u16 h){
    union { u32 u; float f; } v; v.u = ((u32)h) << 16; return v.f;
}

__device__ __forceinline__ void gload_lds16(const u16* g, u16* l){
    __builtin_amdgcn_global_load_lds(
        (const __attribute__((address_space(1))) void*)g,
        (__attribute__((address_space(3))) void*)l, 16, 0, 0);
}

// vectorized 8-element row loads (G13)
__device__ __forceinline__ void load8(const float* p, float* v){
    f32x4 a = *(const f32x4*)p, c = *(const f32x4*)(p+4);
    #pragma unroll
    for (int j=0;j<4;++j){ v[j]=a[j]; v[4+j]=c[j]; }
}
__device__ __forceinline__ void load8(const u16* p, float* v){
    short8v s = *(const short8v*)p;
    #pragma unroll
    for (int j=0;j<8;++j) v[j] = b2f((u16)s[j]);
}

// ---------------- setup: per-state SSM params ----------------
__global__ void setup_kernel(const float* __restrict__ Lre, const float* __restrict__ Lim,
                             const float* __restrict__ log_step,
                             float* __restrict__ prm){
    int p = blockIdx.x*blockDim.x + threadIdx.x;
    if (p >= Pz) return;
    float lr = Lre[p], li = Lim[p];
    float dt = expf(log_step[p]);
    float ar = lr*dt, ai = li*dt;
    float e = expf(ar);
    float Abr = e*cosf(ai), Abi = e*sinf(ai);   // Lambda_bar
    prm[p]        = Abr;
    prm[Pz + p]   = Abi;
    float nr = Abr - 1.0f, ni = Abi;
    float d2 = lr*lr + li*li;
    prm[2*Pz + p] = (nr*lr + ni*li)/d2;   // fRe
    prm[3*Pz + p] = (ni*lr - nr*li)/d2;   // fIm
    float arC = ar*(float)CL, aiC = ai*(float)CL;
    float eC = expf(arC);
    prm[4*Pz + p] = eC*cosf(aiC);         // ApowRe
    prm[5*Pz + p] = eC*sinf(aiC);         // ApowIm
}

// ---------------- merged weight converts (one launch) ----------------
__global__ __launch_bounds__(256) void cvt_all(const float* __restrict__ B_re,
                                               const float* __restrict__ B_im,
                                               const float* __restrict__ C_re,
                                               const float* __restrict__ C_im,
                                               const float* __restrict__ W_enc,
                                               const float* __restrict__ W_dec,
                                               u16* __restrict__ Bcat,
                                               u16* __restrict__ Ccat,
                                               u16* __restrict__ Wenc,
                                               u16* __restrict__ Wdec){
    const int Q = 512*512;
    int i = blockIdx.x*256 + threadIdx.x;
    if (i < Q){ Bcat[i] = f2b(B_re[i]); return; }
    i -= Q;
    if (i < Q){ Bcat[Q + i] = f2b(B_im[i]); return; }
    i -= Q;
    if (i < Q){
        int h = i >> 9, p = i & 511;
        Ccat[(size_t)h*1024 + p]       = f2b(C_re[i]);
        Ccat[(size_t)h*1024 + 512 + p] = f2b(-C_im[i]);
        return;
    }
    i -= Q;
    if (i < 2*Q){ Wenc[i] = f2b(W_enc[i]); return; }
    i -= 2*Q;
    Wdec[i] = f2b(W_dec[i]);
}

// ---------------- LayerNorm: wave-per-row, vectorized (f32|bf16 in -> bf16 out) ----
template<typename T>
__global__ __launch_bounds__(256) void ln_kernel(const T* __restrict__ in,
                                                 const float* __restrict__ w,
                                                 const float* __restrict__ b,
                                                 u16* __restrict__ ob){
    int row = blockIdx.x*4 + (threadIdx.x >> 6);
    int l = threadIdx.x & 63;
    float v[8];
    load8(in + (size_t)row*Hz + l*8, v);
    float s = 0.f, q = 0.f;
    #pragma unroll
    for (int j=0;j<8;++j){ s += v[j]; q += v[j]*v[j]; }
    #pragma unroll
    for (int o=32;o;o>>=1){ s += __shfl_xor(s,o); q += __shfl_xor(q,o); }
    float mu = s * (1.0f/512.0f);
    float rs = rsqrtf(q * (1.0f/512.0f) - mu*mu + EPSf);
    short8v o8;
    #pragma unroll
    for (int j=0;j<8;++j){
        int m = l*8 + j;
        o8[j] = (short)f2b((v[j]-mu)*rs*w[m] + b[m]);
    }
    *(short8v*)&ob[(size_t)row*Hz + l*8] = o8;
}

// ============ 2-phase 128x128 MFMA GEMM (R6-exact, best measured) =============
// C[N,M] = A[N,K] @ Bw[M,K]^T. BM=BN=128, BK=64, 256 threads (4 waves).
// Wave w: all 128 rows x cols [w*32, w*32+32)  -> acc[8][2] f32x4.
// LDS: 2 x (16KB A + 16KB B) = 64KB. SQ_LDS_BANK_CONFLICT = 0 (HW-verified).
#define EB16 0
#define EY   1
#define ERES 2

// stage 128 rows x 64 cols bf16 (16KB); 4 gload_lds per thread (256 thr)
__device__ __forceinline__ void stage128(const u16* __restrict__ src, int ld,
                                         int grow0, int kt, u16* lds){
    int lane = threadIdx.x & 63;
    int w    = threadIdx.x >> 6;                       // 0..3
    #pragma unroll
    for (int q = 0; q < 4; ++q){
        int c = w + q*4;                               // 1KB chunk id, 0..15 (8 rows)
        int r = c*8 + (lane >> 3);                     // row 0..127
        int colE = 8*((lane & 7) ^ ((lane >> 3) & 7)); // swizzled source col (elems)
        const u16* g = src + (size_t)(grow0 + r)*ld + kt + colE;
        gload_lds16(g, lds + c*512);                   // wave-uniform base + lane*16B
    }
}

template<int K, int EPI>
__global__ __launch_bounds__(256, 2)
void gemm2p(const u16* __restrict__ A, const u16* __restrict__ Bw, int M,
            u16* __restrict__ outB,
            const u16* __restrict__ fxB,        // EY: bf16 residual fx
            const float* __restrict__ Dv,       // EY
            const u16* __restrict__ resB,       // ERES
            float* __restrict__ outF)           // ERES
{
    constexpr int NT = K/64;
    __shared__ u16 AL[2][128*64];
    __shared__ u16 BL[2][128*64];

    // XCD-aware bijective swizzle (nwg % 8 == 0 for all our grids)
    int nx = gridDim.x, ny = gridDim.y;
    int nwg = nx*ny;
    int lid = blockIdx.x + blockIdx.y*nx;
    int cpx = nwg >> 3;
    int gdx = (lid & 7)*cpx + (lid >> 3);
    int n0 = (gdx / ny) * 128;
    int m0 = (gdx % ny) * 128;

    int l = threadIdx.x & 63;
    int w = threadIdx.x >> 6;
    int lrow  = l & 15;
    int lcol0 = ((l >> 4)*8) ^ ((l & 7) << 3);   // swizzled u16 col, k-slot 0
    int lcol1 = lcol0 ^ 32;                      // k-slot 1
    int colw  = w*32;

    f32x4 acc[8][2];
    #pragma unroll
    for (int i=0;i<8;++i){ acc[i][0]=(f32x4)(0.f); acc[i][1]=(f32x4)(0.f); }

    // prologue: stage tile 0
    stage128(A,  K, n0, 0, &AL[0][0]);
    stage128(Bw, K, m0, 0, &BL[0][0]);
    __syncthreads();

    for (int T=0; T<NT; ++T){
        int buf = T & 1, nb = buf ^ 1;
        if (T+1 < NT){
            int ktn = (T+1)*64;
            stage128(A,  K, n0, ktn, &AL[nb][0]);
            stage128(Bw, K, m0, ktn, &BL[nb][0]);
        }
        const u16* Ab = &AL[buf][0];
        const u16* Bb = &BL[buf][0];
        bf16x8 bfr[2][2];
        #pragma unroll
        for (int fn=0; fn<2; ++fn){
            bfr[0][fn] = *(const bf16x8*)&Bb[(colw + fn*16 + lrow)*64 + lcol0];
            bfr[1][fn] = *(const bf16x8*)&Bb[(colw + fn*16 + lrow)*64 + lcol1];
        }
        #pragma unroll
        for (int f=0; f<8; ++f){
            bf16x8 a0 = *(const bf16x8*)&Ab[(f*16 + lrow)*64 + lcol0];
            bf16x8 a1 = *(const bf16x8*)&Ab[(f*16 + lrow)*64 + lcol1];
            #pragma unroll
            for (int fn=0; fn<2; ++fn){
                acc[f][fn] = __builtin_amdgcn_mfma_f32_16x16x32_bf16(a0, bfr[0][fn], acc[f][fn], 0,0,0);
                acc[f][fn] = __builtin_amdgcn_mfma_f32_16x16x32_bf16(a1, bfr[1][fn], acc[f][fn], 0,0,0);
            }
        }
        __syncthreads();   // vmcnt(0)+lgkmcnt(0)+barrier; other resident block overlaps
    }

    // epilogue: C layout col=lane&15, row=(lane>>4)*4+q
    int er = (l >> 4) * 4;
    int ec = l & 15;
    #pragma unroll
    for (int fm=0; fm<8; ++fm)
        #pragma unroll
        for (int fn=0; fn<2; ++fn)
            #pragma unroll
            for (int q=0; q<4; ++q){
                int n = n0 + fm*16 + er + q;
                int m = m0 + colw + fn*16 + ec;
                float v = acc[fm][fn][q];
                if (EPI == EB16){
                    outB[(size_t)n*M + m] = f2b(v);
                } else if (EPI == EY){
                    size_t idx = (size_t)n*Hz + m;
                    float fxv = b2f(fxB[idx]);
                    float y = 2.0f*v + Dv[m]*fxv;
                    outB[idx] = f2b(gelu_exact(y) + fxv);
                } else {
                    size_t idx = (size_t)n*Hz + m;
                    outF[idx] = v + b2f(resB[idx]);
                }
            }
}

// ---------------- scan: vectorized short4 (8B) loads, 4 states/thread -------
// g layout: [N][1024], cols [0,512)=Re raw, [512,1024)=Im raw.
// grid Bz*NC*2 blocks x 64 threads; block handles (b, c, p-half), thread 4 states.
__global__ __launch_bounds__(64) void scan_phase1(const u16* __restrict__ g,
                                                  const float* __restrict__ prm,
                                                  float* __restrict__ ERe,
                                                  float* __restrict__ EIm){
    int t = blockIdx.x;
    int ph = t & 1; t >>= 1;
    int c  = t % NC;
    int b  = t / NC;
    int p0 = ph*256 + threadIdx.x*4;
    size_t base = ((size_t)(b*Lz + c*CL))*1024;
    float Ar[4], Ai[4], fr[4], fi[4], xr[4], xi[4];
    #pragma unroll
    for (int j=0;j<4;++j){
        Ar[j]=prm[p0+j]; Ai[j]=prm[Pz+p0+j];
        fr[j]=prm[2*Pz+p0+j]; fi[j]=prm[3*Pz+p0+j];
        xr[j]=0.f; xi[j]=0.f;
    }
    for (int ll=0; ll<CL; ++ll){
        short4v g4 = *(const short4v*)&g[base + p0];
        short4v h4 = *(const short4v*)&g[base + 512 + p0];
        #pragma unroll
        for (int j=0;j<4;++j){
            float gr = b2f((u16)g4[j]), gi = b2f((u16)h4[j]);
            float br = fr[j]*gr - fi[j]*gi;
            float bi = fr[j]*gi + fi[j]*gr;
            float nr = Ar[j]*xr[j] - Ai[j]*xi[j] + br;
            float ni = Ar[j]*xi[j] + Ai[j]*xr[j] + bi;
            xr[j]=nr; xi[j]=ni;
        }
        base += 1024;
    }
    size_t ci = ((size_t)(b*NC + c))*Pz + p0;
    f32x4 er4, ei4;
    #pragma unroll
    for (int j=0;j<4;++j){ er4[j]=xr[j]; ei4[j]=xi[j]; }
    *(f32x4*)&ERe[ci] = er4;
    *(f32x4*)&EIm[ci] = ei4;
}

__global__ __launch_bounds__(256) void scan_combine(const float* __restrict__ ERe,
                                                    const float* __restrict__ EIm,
                                                    const float* __restrict__ prm,
                                                    float* __restrict__ SinRe,
                                                    float* __restrict__ SinIm){
    int gt = blockIdx.x*256 + threadIdx.x;   // over B*P
    int b = gt / Pz, p = gt % Pz;
    float Ar = prm[4*Pz+p], Ai = prm[5*Pz+p];
    float Sr = 0.f, Si = 0.f;
    for (int c = 0; c < NC; ++c) {
        size_t idx = ((size_t)(b*NC + c))*Pz + p;
        SinRe[idx] = Sr; SinIm[idx] = Si;
        float er = ERe[idx], ei = EIm[idx];
        float nr = Ar*Sr - Ai*Si + er;
        float ni = Ar*Si + Ai*Sr + ei;
        Sr = nr; Si = ni;
    }
}

// overwrites g with xs (bf16, same [re|im] layout)
__global__ __launch_bounds__(64) void scan_phase2(u16* __restrict__ g,
                                                  const float* __restrict__ prm,
                                                  const float* __restrict__ SinRe,
                                                  const float* __restrict__ SinIm){
    int t = blockIdx.x;
    int ph = t & 1; t >>= 1;
    int c  = t % NC;
    int b  = t / NC;
    int p0 = ph*256 + threadIdx.x*4;
    size_t base = ((size_t)(b*Lz + c*CL))*1024;
    size_t ci = ((size_t)(b*NC + c))*Pz + p0;
    float Ar[4], Ai[4], fr[4], fi[4], xr[4], xi[4];
    f32x4 sr4 = *(const f32x4*)&SinRe[ci];
    f32x4 si4 = *(const f32x4*)&SinIm[ci];
    #pragma unroll
    for (int j=0;j<4;++j){
        Ar[j]=prm[p0+j]; Ai[j]=prm[Pz+p0+j];
        fr[j]=prm[2*Pz+p0+j]; fi[j]=prm[3*Pz+p0+j];
        xr[j]=sr4[j]; xi[j]=si4[j];
    }
    for (int ll=0; ll<CL; ++ll){
        short4v g4 = *(const short4v*)&g[base + p0];
        short4v h4 = *(const short4v*)&g[base + 512 + p0];
        short4v o4, p4;
        #pragma unroll
        for (int j=0;j<4;++j){
            float gr = b2f((u16)g4[j]), gi = b2f((u16)h4[j]);
            float br = fr[j]*gr - fi[j]*gi;
            float bi = fr[j]*gi + fi[j]*gr;
            float nr = Ar[j]*xr[j] - Ai[j]*xi[j] + br;
            float ni = Ar[j]*xi[j] + Ai[j]*xr[j] + bi;
            xr[j]=nr; xi[j]=ni;
            o4[j] = (short)f2b(nr);
            p4[j] = (short)f2b(ni);
        }
        *(short4v*)&g[base + p0]       = o4;
        *(short4v*)&g[base + 512 + p0] = p4;
        base += 1024;
    }
}

// ---------------- GEGLU elementwise, short8 vectorized: ff = a * gelu(g) -----
__global__ __launch_bounds__(256) void geglu_kernel(const u16* __restrict__ e,
                                                    u16* __restrict__ ff){
    int i = blockIdx.x*256 + threadIdx.x;   // over N*64 vectors
    int n = i >> 6, mc = (i & 63)*8;
    short8v a8 = *(const short8v*)&e[(size_t)n*1024 + mc];
    short8v g8 = *(const short8v*)&e[(size_t)n*1024 + 512 + mc];
    short8v o8;
    #pragma unroll
    for (int j=0;j<8;++j)
        o8[j] = (short)f2b(b2f((u16)a8[j]) * gelu_exact(b2f((u16)g8[j])));
    *(short8v*)&ff[(size_t)n*512 + mc] = o8;
}

extern "C" void kernel_launch(void* const* d_in, const int* in_sizes, int n_in,
                              void* d_out, int out_size, void* d_ws, size_t ws_size,
                              hipStream_t stream) {
    const float* x        = (const float*)d_in[0];
    const float* ln1_w    = (const float*)d_in[1];
    const float* ln1_b    = (const float*)d_in[2];
    const float* Lre      = (const float*)d_in[3];
    const float* Lim      = (const float*)d_in[4];
    const float* B_re     = (const float*)d_in[5];
    const float* B_im     = (const float*)d_in[6];
    const float* C_re     = (const float*)d_in[7];
    const float* C_im     = (const float*)d_in[8];
    const float* Dv       = (const float*)d_in[9];
    const float* log_step = (const float*)d_in[10];
    const float* ln2_w    = (const float*)d_in[11];
    const float* ln2_b    = (const float*)d_in[12];
    const float* W_enc    = (const float*)d_in[13];
    const float* W_dec    = (const float*)d_in[14];
    float* out = (float*)d_out;

    const size_t NH = (size_t)Nz*Hz;   // 8388608
    char* W = (char*)d_ws;
    u16*   fxb  = (u16*)  (W);                    // [N,512] bf16: fx, later ff
    u16*   g    = (u16*)  (W + NH*2);             // [N,1024] bf16: g -> xs -> e
    u16*   hb   = (u16*)  (W + NH*6);             // [N,512] bf16: h
    u16*   fx2b = (u16*)  (W + NH*8);             // [N,512] bf16: fx2
    float* ERe  = (float*)(W + NH*10);
    float* EIm  = ERe + CS;
    float* SinRe= EIm + CS;
    float* SinIm= SinRe + CS;
    float* prm  = SinIm + CS;                     // 6*Pz f32
    u16*   Bcat = (u16*)(prm + 6*Pz);             // [1024,512]
    u16*   Ccat = Bcat + 1024*512;                // [512,1024]
    u16*   Wenc = Ccat + 512*1024;                // [1024,512]
    u16*   Wdec = Wenc + 1024*512;                // [512,512]

    setup_kernel<<<dim3(2), dim3(256), 0, stream>>>(Lre, Lim, log_step, prm);

    cvt_all<<<dim3(6*1024), dim3(256), 0, stream>>>(B_re, B_im, C_re, C_im, W_enc, W_dec,
                                                    Bcat, Ccat, Wenc, Wdec);

    // LN1: x -> fxb (bf16), wave-per-row vectorized
    ln_kernel<float><<<dim3(Nz/4), dim3(256), 0, stream>>>(x, ln1_w, ln1_b, fxb);

    // GEMM1: g = fxb @ Bcat^T   [N,1024]   grid 128x8 = 1024 blocks
    gemm2p<512,EB16><<<dim3(Nz/128, 1024/128), dim3(256), 0, stream>>>(
        fxb, Bcat, 1024, g, nullptr, nullptr, nullptr, nullptr);

    // scan: g (raw) -> xs (in place), f-scaling applied on load
    scan_phase1<<<dim3(Bz*NC*2), dim3(64), 0, stream>>>(g, prm, ERe, EIm);
    scan_combine<<<dim3((Bz*Pz)/256), dim3(256), 0, stream>>>(ERe, EIm, prm, SinRe, SinIm);
    scan_phase2<<<dim3(Bz*NC*2), dim3(64), 0, stream>>>(g, prm, SinRe, SinIm);

    // GEMM2 (Y): h = gelu(2*(xs@Ccat^T) + D*fx) + fx -> hb   grid 128x4 = 512
    gemm2p<1024,EY><<<dim3(Nz/128, 512/128), dim3(256), 0, stream>>>(
        g, Ccat, 512, hb, fxb, Dv, nullptr, nullptr);

    // LN2: hb -> fx2b (bf16)
    ln_kernel<u16><<<dim3(Nz/4), dim3(256), 0, stream>>>(hb, ln2_w, ln2_b, fx2b);

    // GEMM3: e = fx2b @ Wenc^T  [N,1024]  grid 128x8 = 1024
    gemm2p<512,EB16><<<dim3(Nz/128, 1024/128), dim3(256), 0, stream>>>(
        fx2b, Wenc, 1024, g, nullptr, nullptr, nullptr, nullptr);

    // GEGLU: ff = a * gelu(gg)  (over fxb slot), short8 vectorized
    geglu_kernel<<<dim3(Nz*64/256), dim3(256), 0, stream>>>(g, fxb);

    // GEMM4: out = ff @ Wdec^T + fx2   grid 128x4 = 512
    gemm2p<512,ERES><<<dim3(Nz/128, 512/128), dim3(256), 0, stream>>>(
        fxb, Wdec, 512, nullptr, nullptr, nullptr, fx2b, out);
}

// Round 12
// 185.635 us; speedup vs baseline: 1.2300x; 1.0217x over previous
//
#include <hip/hip_runtime.h>
#include <math.h>

// (B,L,H,P) = (4,4096,512,512)
#define Bz 4
#define Lz 4096
#define Hz 512
#define Pz 512
#define Nz (Bz*Lz)          // 16384 rows
#define CL 64               // scan chunk length
#define NC (Lz/CL)          // 64 chunks
#define CS (Bz*NC*Pz)       // 131072 carry slots
#define EPSf 1e-5f

typedef unsigned short u16;
typedef unsigned int   u32;
typedef __attribute__((ext_vector_type(8))) short bf16x8;
typedef __attribute__((ext_vector_type(8))) short short8v;
typedef __attribute__((ext_vector_type(4))) float f32x4;

__device__ __forceinline__ float gelu_exact(float x){
    return 0.5f * x * (1.0f + erff(x * 0.70710678118654752f));
}
__device__ __forceinline__ u16 f2b(float f){
    union { float f; u32 u; } v; v.f = f;
    u32 u = v.u;
    u32 r = (u + 0x7FFFu + ((u >> 16) & 1u)) >> 16;   // RTNE
    return (u16)r;
}
__device__ __forceinline__ float b2f(u16 h){
    union { u32 u; float f; } v; v.u = ((u32)h) << 16; return v.f;
}

__device__ __forceinline__ void gload_lds16(const u16* g, u16* l){
    __builtin_amdgcn_global_load_lds(
        (const __attribute__((address_space(1))) void*)g,
        (__attribute__((address_space(3))) void*)l, 16, 0, 0);
}

// vectorized 8-element row loads (G13)
__device__ __forceinline__ void load8(const float* p, float* v){
    f32x4 a = *(const f32x4*)p, c = *(const f32x4*)(p+4);
    #pragma unroll
    for (int j=0;j<4;++j){ v[j]=a[j]; v[4+j]=c[j]; }
}
__device__ __forceinline__ void load8(const u16* p, float* v){
    short8v s = *(const short8v*)p;
    #pragma unroll
    for (int j=0;j<8;++j) v[j] = b2f((u16)s[j]);
}

// ---------------- setup: per-state SSM params ----------------
__global__ void setup_kernel(const float* __restrict__ Lre, const float* __restrict__ Lim,
                             const float* __restrict__ log_step,
                             float* __restrict__ prm){
    int p = blockIdx.x*blockDim.x + threadIdx.x;
    if (p >= Pz) return;
    float lr = Lre[p], li = Lim[p];
    float dt = expf(log_step[p]);
    float ar = lr*dt, ai = li*dt;
    float e = expf(ar);
    float Abr = e*cosf(ai), Abi = e*sinf(ai);   // Lambda_bar
    prm[p]        = Abr;
    prm[Pz + p]   = Abi;
    float nr = Abr - 1.0f, ni = Abi;
    float d2 = lr*lr + li*li;
    prm[2*Pz + p] = (nr*lr + ni*li)/d2;   // fRe
    prm[3*Pz + p] = (ni*lr - nr*li)/d2;   // fIm
    float arC = ar*(float)CL, aiC = ai*(float)CL;
    float eC = expf(arC);
    prm[4*Pz + p] = eC*cosf(aiC);         // ApowRe
    prm[5*Pz + p] = eC*sinf(aiC);         // ApowIm
}

// ---------------- merged weight converts (one launch) ----------------
// Interleaved complex layout: g col 2p = Re_p, 2p+1 = Im_p.
// Bcat row 2p = B_re row p, row 2p+1 = B_im row p  ([1024,512])
// Ccat col 2p = C_re col p, col 2p+1 = -C_im col p ([512,1024])
__global__ __launch_bounds__(256) void cvt_all(const float* __restrict__ B_re,
                                               const float* __restrict__ B_im,
                                               const float* __restrict__ C_re,
                                               const float* __restrict__ C_im,
                                               const float* __restrict__ W_enc,
                                               const float* __restrict__ W_dec,
                                               u16* __restrict__ Bcat,
                                               u16* __restrict__ Ccat,
                                               u16* __restrict__ Wenc,
                                               u16* __restrict__ Wdec){
    const int Q = 512*512;
    int i = blockIdx.x*256 + threadIdx.x;
    if (i < Q){ int p=i>>9, h=i&511; Bcat[(size_t)(2*p)*512 + h]   = f2b(B_re[i]); return; }
    i -= Q;
    if (i < Q){ int p=i>>9, h=i&511; Bcat[(size_t)(2*p+1)*512 + h] = f2b(B_im[i]); return; }
    i -= Q;
    if (i < Q){
        int h = i >> 9, p = i & 511;
        Ccat[(size_t)h*1024 + 2*p]     = f2b(C_re[i]);
        Ccat[(size_t)h*1024 + 2*p + 1] = f2b(-C_im[i]);
        return;
    }
    i -= Q;
    if (i < 2*Q){ Wenc[i] = f2b(W_enc[i]); return; }
    i -= 2*Q;
    Wdec[i] = f2b(W_dec[i]);
}

// ---------------- LayerNorm: wave-per-row, vectorized ----------------
template<typename T>
__global__ __launch_bounds__(256) void ln_kernel(const T* __restrict__ in,
                                                 const float* __restrict__ w,
                                                 const float* __restrict__ b,
                                                 u16* __restrict__ ob){
    int row = blockIdx.x*4 + (threadIdx.x >> 6);
    int l = threadIdx.x & 63;
    float v[8];
    load8(in + (size_t)row*Hz + l*8, v);
    float s = 0.f, q = 0.f;
    #pragma unroll
    for (int j=0;j<8;++j){ s += v[j]; q += v[j]*v[j]; }
    #pragma unroll
    for (int o=32;o;o>>=1){ s += __shfl_xor(s,o); q += __shfl_xor(q,o); }
    float mu = s * (1.0f/512.0f);
    float rs = rsqrtf(q * (1.0f/512.0f) - mu*mu + EPSf);
    short8v o8;
    #pragma unroll
    for (int j=0;j<8;++j){
        int m = l*8 + j;
        o8[j] = (short)f2b((v[j]-mu)*rs*w[m] + b[m]);
    }
    *(short8v*)&ob[(size_t)row*Hz + l*8] = o8;
}

// ============ 2-phase 128x128 MFMA GEMM core (R6-exact) =============
// LDS tiles [128][64] bf16, 0-conflict swizzle (HW-verified):
// stage colE = 8*((lane&7)^((lane>>3)&7)); read lcol = ((l>>4)*8)^((l&7)<<3).
#define EB16 0
#define EY   1
#define ERES 2

__device__ __forceinline__ void stage128(const u16* __restrict__ src, int ld,
                                         int grow0, int kt, u16* lds){
    int lane = threadIdx.x & 63;
    int w    = threadIdx.x >> 6;                       // 0..3
    #pragma unroll
    for (int q = 0; q < 4; ++q){
        int c = w + q*4;                               // 1KB chunk id, 0..15 (8 rows)
        int r = c*8 + (lane >> 3);                     // row 0..127
        int colE = 8*((lane & 7) ^ ((lane >> 3) & 7)); // swizzled source col (elems)
        const u16* g = src + (size_t)(grow0 + r)*ld + kt + colE;
        gload_lds16(g, lds + c*512);                   // wave-uniform base + lane*16B
    }
}

template<int K, int EPI>
__global__ __launch_bounds__(256, 2)
void gemm2p(const u16* __restrict__ A, const u16* __restrict__ Bw, int M,
            u16* __restrict__ outB,
            const u16* __restrict__ fxB,        // EY: bf16 residual fx
            const float* __restrict__ Dv,       // EY
            const u16* __restrict__ resB,       // ERES
            float* __restrict__ outF)           // ERES
{
    constexpr int NT = K/64;
    __shared__ u16 AL[2][128*64];
    __shared__ u16 BL[2][128*64];

    int nx = gridDim.x, ny = gridDim.y;
    int nwg = nx*ny;
    int lid = blockIdx.x + blockIdx.y*nx;
    int cpx = nwg >> 3;
    int gdx = (lid & 7)*cpx + (lid >> 3);
    int n0 = (gdx / ny) * 128;
    int m0 = (gdx % ny) * 128;

    int l = threadIdx.x & 63;
    int w = threadIdx.x >> 6;
    int lrow  = l & 15;
    int lcol0 = ((l >> 4)*8) ^ ((l & 7) << 3);
    int lcol1 = lcol0 ^ 32;
    int colw  = w*32;

    f32x4 acc[8][2];
    #pragma unroll
    for (int i=0;i<8;++i){ acc[i][0]=(f32x4)(0.f); acc[i][1]=(f32x4)(0.f); }

    stage128(A,  K, n0, 0, &AL[0][0]);
    stage128(Bw, K, m0, 0, &BL[0][0]);
    __syncthreads();

    for (int T=0; T<NT; ++T){
        int buf = T & 1, nb = buf ^ 1;
        if (T+1 < NT){
            int ktn = (T+1)*64;
            stage128(A,  K, n0, ktn, &AL[nb][0]);
            stage128(Bw, K, m0, ktn, &BL[nb][0]);
        }
        const u16* Ab = &AL[buf][0];
        const u16* Bb = &BL[buf][0];
        bf16x8 bfr[2][2];
        #pragma unroll
        for (int fn=0; fn<2; ++fn){
            bfr[0][fn] = *(const bf16x8*)&Bb[(colw + fn*16 + lrow)*64 + lcol0];
            bfr[1][fn] = *(const bf16x8*)&Bb[(colw + fn*16 + lrow)*64 + lcol1];
        }
        #pragma unroll
        for (int f=0; f<8; ++f){
            bf16x8 a0 = *(const bf16x8*)&Ab[(f*16 + lrow)*64 + lcol0];
            bf16x8 a1 = *(const bf16x8*)&Ab[(f*16 + lrow)*64 + lcol1];
            #pragma unroll
            for (int fn=0; fn<2; ++fn){
                acc[f][fn] = __builtin_amdgcn_mfma_f32_16x16x32_bf16(a0, bfr[0][fn], acc[f][fn], 0,0,0);
                acc[f][fn] = __builtin_amdgcn_mfma_f32_16x16x32_bf16(a1, bfr[1][fn], acc[f][fn], 0,0,0);
            }
        }
        __syncthreads();
    }

    int er = (l >> 4) * 4;
    int ec = l & 15;
    #pragma unroll
    for (int fm=0; fm<8; ++fm)
        #pragma unroll
        for (int fn=0; fn<2; ++fn)
            #pragma unroll
            for (int q=0; q<4; ++q){
                int n = n0 + fm*16 + er + q;
                int m = m0 + colw + fn*16 + ec;
                float v = acc[fm][fn][q];
                if (EPI == EB16){
                    outB[(size_t)n*M + m] = f2b(v);
                } else if (EPI == EY){
                    size_t idx = (size_t)n*Hz + m;
                    float fxv = b2f(fxB[idx]);
                    float y = 2.0f*v + Dv[m]*fxv;
                    outB[idx] = f2b(gelu_exact(y) + fxv);
                } else {
                    size_t idx = (size_t)n*Hz + m;
                    outF[idx] = v + b2f(resB[idx]);
                }
            }
}

// ---- GEMM1 + fused scan-phase1: g = fx@Bcat^T (interleaved), E per chunk ----
// Block = 128 rows (2 scan-chunks of one batch) x 128 cols (64 complex states).
// After the K-loop, acc -> LDS bf16 tile (aliases dead staging bufs), then
// 128 threads scan 64 rows each (state p, chunk h) and emit E carries.
__global__ __launch_bounds__(256, 2)
void gemm1_scan(const u16* __restrict__ A, const u16* __restrict__ Bw,
                u16* __restrict__ outB,
                const float* __restrict__ prm,
                float* __restrict__ ERe, float* __restrict__ EIm)
{
    constexpr int K = 512, NT = K/64;
    __shared__ u16 AL[2][128*64];
    __shared__ u16 BL[2][128*64];

    int nx = gridDim.x, ny = gridDim.y;
    int nwg = nx*ny;
    int lid = blockIdx.x + blockIdx.y*nx;
    int cpx = nwg >> 3;
    int gdx = (lid & 7)*cpx + (lid >> 3);
    int n0 = (gdx / ny) * 128;
    int m0 = (gdx % ny) * 128;

    int l = threadIdx.x & 63;
    int w = threadIdx.x >> 6;
    int lrow  = l & 15;
    int lcol0 = ((l >> 4)*8) ^ ((l & 7) << 3);
    int lcol1 = lcol0 ^ 32;
    int colw  = w*32;

    f32x4 acc[8][2];
    #pragma unroll
    for (int i=0;i<8;++i){ acc[i][0]=(f32x4)(0.f); acc[i][1]=(f32x4)(0.f); }

    stage128(A,  K, n0, 0, &AL[0][0]);
    stage128(Bw, K, m0, 0, &BL[0][0]);
    __syncthreads();

    for (int T=0; T<NT; ++T){
        int buf = T & 1, nb = buf ^ 1;
        if (T+1 < NT){
            int ktn = (T+1)*64;
            stage128(A,  K, n0, ktn, &AL[nb][0]);
            stage128(Bw, K, m0, ktn, &BL[nb][0]);
        }
        const u16* Ab = &AL[buf][0];
        const u16* Bb = &BL[buf][0];
        bf16x8 bfr[2][2];
        #pragma unroll
        for (int fn=0; fn<2; ++fn){
            bfr[0][fn] = *(const bf16x8*)&Bb[(colw + fn*16 + lrow)*64 + lcol0];
            bfr[1][fn] = *(const bf16x8*)&Bb[(colw + fn*16 + lrow)*64 + lcol1];
        }
        #pragma unroll
        for (int f=0; f<8; ++f){
            bf16x8 a0 = *(const bf16x8*)&Ab[(f*16 + lrow)*64 + lcol0];
            bf16x8 a1 = *(const bf16x8*)&Ab[(f*16 + lrow)*64 + lcol1];
            #pragma unroll
            for (int fn=0; fn<2; ++fn){
                acc[f][fn] = __builtin_amdgcn_mfma_f32_16x16x32_bf16(a0, bfr[0][fn], acc[f][fn], 0,0,0);
                acc[f][fn] = __builtin_amdgcn_mfma_f32_16x16x32_bf16(a1, bfr[1][fn], acc[f][fn], 0,0,0);
            }
        }
        __syncthreads();
    }

    // epilogue: write g (global) + gt (LDS, aliases AL — dead after last barrier)
    u16* gt = (u16*)AL;     // [128][128] u16 = 32 KB
    int er = (l >> 4) * 4;
    int ec = l & 15;
    #pragma unroll
    for (int fm=0; fm<8; ++fm)
        #pragma unroll
        for (int fn=0; fn<2; ++fn)
            #pragma unroll
            for (int q=0; q<4; ++q){
                int rr = fm*16 + er + q;
                int cc = colw + fn*16 + ec;
                u16 hv = f2b(acc[fm][fn][q]);
                outB[(size_t)(n0 + rr)*1024 + (m0 + cc)] = hv;
                gt[rr*128 + cc] = hv;
            }
    __syncthreads();

    // fused scan phase 1: thread (p = tid&63, h = tid>>6) scans 64 rows
    int tid = threadIdx.x;
    if (tid < 128){
        int p = tid & 63, h = tid >> 6;
        int P = (m0 >> 1) + p;
        int b = n0 >> 12;
        int c = ((n0 & 4095) >> 6) + h;
        float Ar = prm[P], Ai = prm[Pz+P];
        float fre = prm[2*Pz+P], fim = prm[3*Pz+P];
        float xr = 0.f, xi = 0.f;
        int base = h*64*128 + 2*p;
        #pragma unroll 8
        for (int r = 0; r < 64; ++r){
            u32 v = *(const u32*)&gt[base + r*128];
            float gr = b2f((u16)(v & 0xffff));
            float gi = b2f((u16)(v >> 16));
            float br = fre*gr - fim*gi;
            float bi = fre*gi + fim*gr;
            float nr2 = Ar*xr - Ai*xi + br;
            float ni2 = Ar*xi + Ai*xr + bi;
            xr = nr2; xi = ni2;
        }
        size_t ci = ((size_t)(b*NC + c))*Pz + P;
        ERe[ci] = xr; EIm[ci] = xi;
    }
}

// ---- GEMM3 + fused GEGLU: ff = (fx2@Wa^T) * gelu(fx2@Wg^T) ----
// Block = 128 rows x 64 ff-cols. Virtual B rows: 16-row groups alternate
// a-rows (Wenc[m0+..]) and g-rows (Wenc[512+m0+..]); wave w's fn=0 frag is
// the a-col w*16+ec, fn=1 the matching g-col -> multiply in-register.
__device__ __forceinline__ void stageWglu(const u16* __restrict__ src, int m0,
                                          int kt, u16* lds){
    int lane = threadIdx.x & 63;
    int w    = threadIdx.x >> 6;
    #pragma unroll
    for (int q = 0; q < 4; ++q){
        int c = w + q*4;
        int r = c*8 + (lane >> 3);                     // virtual row 0..127
        int rb = r >> 4;                                // 16-row group
        int grow = (rb & 1) ? (512 + m0 + ((rb>>1)<<4) + (r & 15))
                            : (      m0 + ((rb>>1)<<4) + (r & 15));
        int colE = 8*((lane & 7) ^ ((lane >> 3) & 7));
        gload_lds16(src + (size_t)grow*512 + kt + colE, lds + c*512);
    }
}

__global__ __launch_bounds__(256, 2)
void gemm3glu(const u16* __restrict__ A, const u16* __restrict__ Wenc,
              u16* __restrict__ outB)
{
    constexpr int K = 512, NT = K/64;
    __shared__ u16 AL[2][128*64];
    __shared__ u16 BL[2][128*64];

    int nx = gridDim.x, ny = gridDim.y;
    int nwg = nx*ny;
    int lid = blockIdx.x + blockIdx.y*nx;
    int cpx = nwg >> 3;
    int gdx = (lid & 7)*cpx + (lid >> 3);
    int n0 = (gdx / ny) * 128;
    int m0 = (gdx % ny) * 64;

    int l = threadIdx.x & 63;
    int w = threadIdx.x >> 6;
    int lrow  = l & 15;
    int lcol0 = ((l >> 4)*8) ^ ((l & 7) << 3);
    int lcol1 = lcol0 ^ 32;
    int colw  = w*32;

    f32x4 acc[8][2];
    #pragma unroll
    for (int i=0;i<8;++i){ acc[i][0]=(f32x4)(0.f); acc[i][1]=(f32x4)(0.f); }

    stage128(A, K, n0, 0, &AL[0][0]);
    stageWglu(Wenc, m0, 0, &BL[0][0]);
    __syncthreads();

    for (int T=0; T<NT; ++T){
        int buf = T & 1, nb = buf ^ 1;
        if (T+1 < NT){
            int ktn = (T+1)*64;
            stage128(A, K, n0, ktn, &AL[nb][0]);
            stageWglu(Wenc, m0, ktn, &BL[nb][0]);
        }
        const u16* Ab = &AL[buf][0];
        const u16* Bb = &BL[buf][0];
        bf16x8 bfr[2][2];
        #pragma unroll
        for (int fn=0; fn<2; ++fn){
            bfr[0][fn] = *(const bf16x8*)&Bb[(colw + fn*16 + lrow)*64 + lcol0];
            bfr[1][fn] = *(const bf16x8*)&Bb[(colw + fn*16 + lrow)*64 + lcol1];
        }
        #pragma unroll
        for (int f=0; f<8; ++f){
            bf16x8 a0 = *(const bf16x8*)&Ab[(f*16 + lrow)*64 + lcol0];
            bf16x8 a1 = *(const bf16x8*)&Ab[(f*16 + lrow)*64 + lcol1];
            #pragma unroll
            for (int fn=0; fn<2; ++fn){
                acc[f][fn] = __builtin_amdgcn_mfma_f32_16x16x32_bf16(a0, bfr[0][fn], acc[f][fn], 0,0,0);
                acc[f][fn] = __builtin_amdgcn_mfma_f32_16x16x32_bf16(a1, bfr[1][fn], acc[f][fn], 0,0,0);
            }
        }
        __syncthreads();
    }

    // epilogue: ff = a * gelu(g), col = m0 + w*16 + ec
    int er = (l >> 4) * 4;
    int ec = l & 15;
    int col = m0 + w*16 + ec;
    #pragma unroll
    for (int fm=0; fm<8; ++fm)
        #pragma unroll
        for (int q=0; q<4; ++q){
            int n = n0 + fm*16 + er + q;
            float ffv = acc[fm][0][q] * gelu_exact(acc[fm][1][q]);
            outB[(size_t)n*Hz + col] = f2b(ffv);
        }
}

// ---------------- scan combine (unchanged) ----------------
__global__ __launch_bounds__(256) void scan_combine(const float* __restrict__ ERe,
                                                    const float* __restrict__ EIm,
                                                    const float* __restrict__ prm,
                                                    float* __restrict__ SinRe,
                                                    float* __restrict__ SinIm){
    int gt = blockIdx.x*256 + threadIdx.x;   // over B*P
    int b = gt / Pz, p = gt % Pz;
    float Ar = prm[4*Pz+p], Ai = prm[5*Pz+p];
    float Sr = 0.f, Si = 0.f;
    for (int c = 0; c < NC; ++c) {
        size_t idx = ((size_t)(b*NC + c))*Pz + p;
        SinRe[idx] = Sr; SinIm[idx] = Si;
        float er = ERe[idx], ei = EIm[idx];
        float nr = Ar*Sr - Ai*Si + er;
        float ni = Ar*Si + Ai*Sr + ei;
        Sr = nr; Si = ni;
    }
}

// ---------------- scan phase2: interleaved, short8 (16B) per row ------------
// Thread handles 4 complex states (cols 2p0..2p0+7); overwrites g with xs.
__global__ __launch_bounds__(64) void scan_phase2(u16* __restrict__ g,
                                                  const float* __restrict__ prm,
                                                  const float* __restrict__ SinRe,
                                                  const float* __restrict__ SinIm){
    int t = blockIdx.x;
    int ph = t & 1; t >>= 1;
    int c  = t % NC;
    int b  = t / NC;
    int p0 = ph*256 + threadIdx.x*4;         // first of 4 states
    int cb = 2*p0;                            // u16 col base (8 u16 = 16B)
    size_t base = ((size_t)(b*Lz + c*CL))*1024;
    size_t ci = ((size_t)(b*NC + c))*Pz + p0;
    float Ar[4], Ai[4], fr[4], fi[4], xr[4], xi[4];
    f32x4 sr4 = *(const f32x4*)&SinRe[ci];
    f32x4 si4 = *(const f32x4*)&SinIm[ci];
    #pragma unroll
    for (int j=0;j<4;++j){
        Ar[j]=prm[p0+j]; Ai[j]=prm[Pz+p0+j];
        fr[j]=prm[2*Pz+p0+j]; fi[j]=prm[3*Pz+p0+j];
        xr[j]=sr4[j]; xi[j]=si4[j];
    }
    for (int ll=0; ll<CL; ++ll){
        short8v v8 = *(const short8v*)&g[base + cb];
        short8v o8;
        #pragma unroll
        for (int j=0;j<4;++j){
            float gr = b2f((u16)v8[2*j]), gi = b2f((u16)v8[2*j+1]);
            float br = fr[j]*gr - fi[j]*gi;
            float bi = fr[j]*gi + fi[j]*gr;
            float nr = Ar[j]*xr[j] - Ai[j]*xi[j] + br;
            float ni = Ar[j]*xi[j] + Ai[j]*xr[j] + bi;
            xr[j]=nr; xi[j]=ni;
            o8[2*j]   = (short)f2b(nr);
            o8[2*j+1] = (short)f2b(ni);
        }
        *(short8v*)&g[base + cb] = o8;
        base += 1024;
    }
}

extern "C" void kernel_launch(void* const* d_in, const int* in_sizes, int n_in,
                              void* d_out, int out_size, void* d_ws, size_t ws_size,
                              hipStream_t stream) {
    const float* x        = (const float*)d_in[0];
    const float* ln1_w    = (const float*)d_in[1];
    const float* ln1_b    = (const float*)d_in[2];
    const float* Lre      = (const float*)d_in[3];
    const float* Lim      = (const float*)d_in[4];
    const float* B_re     = (const float*)d_in[5];
    const float* B_im     = (const float*)d_in[6];
    const float* C_re     = (const float*)d_in[7];
    const float* C_im     = (const float*)d_in[8];
    const float* Dv       = (const float*)d_in[9];
    const float* log_step = (const float*)d_in[10];
    const float* ln2_w    = (const float*)d_in[11];
    const float* ln2_b    = (const float*)d_in[12];
    const float* W_enc    = (const float*)d_in[13];
    const float* W_dec    = (const float*)d_in[14];
    float* out = (float*)d_out;

    const size_t NH = (size_t)Nz*Hz;   // 8388608
    char* W = (char*)d_ws;
    u16*   fxb  = (u16*)  (W);                    // [N,512] bf16: fx, later ff
    u16*   g    = (u16*)  (W + NH*2);             // [N,1024] bf16 interleaved: g -> xs
    u16*   hb   = (u16*)  (W + NH*6);             // [N,512] bf16: h
    u16*   fx2b = (u16*)  (W + NH*8);             // [N,512] bf16: fx2
    float* ERe  = (float*)(W + NH*10);
    float* EIm  = ERe + CS;
    float* SinRe= EIm + CS;
    float* SinIm= SinRe + CS;
    float* prm  = SinIm + CS;                     // 6*Pz f32
    u16*   Bcat = (u16*)(prm + 6*Pz);             // [1024,512] interleaved rows
    u16*   Ccat = Bcat + 1024*512;                // [512,1024] interleaved cols
    u16*   Wenc = Ccat + 512*1024;                // [1024,512]
    u16*   Wdec = Wenc + 1024*512;                // [512,512]

    setup_kernel<<<dim3(2), dim3(256), 0, stream>>>(Lre, Lim, log_step, prm);

    cvt_all<<<dim3(6*1024), dim3(256), 0, stream>>>(B_re, B_im, C_re, C_im, W_enc, W_dec,
                                                    Bcat, Ccat, Wenc, Wdec);

    // LN1: x -> fxb (bf16)
    ln_kernel<float><<<dim3(Nz/4), dim3(256), 0, stream>>>(x, ln1_w, ln1_b, fxb);

    // GEMM1 + scan-phase1 fused: g (interleaved) + E carries
    gemm1_scan<<<dim3(Nz/128, 1024/128), dim3(256), 0, stream>>>(
        fxb, Bcat, g, prm, ERe, EIm);

    // scan combine + phase2 (in place over g)
    scan_combine<<<dim3((Bz*Pz)/256), dim3(256), 0, stream>>>(ERe, EIm, prm, SinRe, SinIm);
    scan_phase2<<<dim3(Bz*NC*2), dim3(64), 0, stream>>>(g, prm, SinRe, SinIm);

    // GEMM2 (Y): h = gelu(2*(xs@Ccat^T) + D*fx) + fx -> hb
    gemm2p<1024,EY><<<dim3(Nz/128, 512/128), dim3(256), 0, stream>>>(
        g, Ccat, 512, hb, fxb, Dv, nullptr, nullptr);

    // LN2: hb -> fx2b (bf16)
    ln_kernel<u16><<<dim3(Nz/4), dim3(256), 0, stream>>>(hb, ln2_w, ln2_b, fx2b);

    // GEMM3 + GEGLU fused: ff -> fxb
    gemm3glu<<<dim3(Nz/128, 8), dim3(256), 0, stream>>>(fx2b, Wenc, fxb);

    // GEMM4: out = ff @ Wdec^T + fx2
    gemm2p<512,ERES><<<dim3(Nz/128, 512/128), dim3(256), 0, stream>>>(
        fxb, Wdec, 512, nullptr, nullptr, nullptr, fx2b, out);
}